// Round 4
// baseline (392.042 us; speedup 1.0000x reference)
//
#include <hip/hip_runtime.h>
#include <hip/hip_bf16.h>

#define DEV static __device__ __forceinline__

typedef short frag8 __attribute__((ext_vector_type(8)));
typedef float accf4 __attribute__((ext_vector_type(4)));

// Problem constants: B=8, P=576, D=1024, H=16, HD=64, HID=4096, BP=4608, BH=128

DEV unsigned short f2bf(float f){
  union { float f; unsigned int u; } v; v.f = f;
  unsigned int r = v.u + 0x7fffu + ((v.u >> 16) & 1u);
  return (unsigned short)(r >> 16);
}

DEV void gload16(const void* g, void* l){
  __builtin_amdgcn_global_load_lds((const __attribute__((address_space(1))) void*)g,
                                   (__attribute__((address_space(3))) void*)l, 16, 0, 0);
}

DEV float gelu_tanh(float x){
  float u = 0.7978845608028654f * (x + 0.044715f * x * x * x);
  float e = __expf(2.0f * u);
  float th = 1.0f - 2.0f / (e + 1.0f);   // tanh(u), inf-safe
  return 0.5f * x * (1.0f + th);
}

// ---------------- weight cast + transpose: W[K,N] f32 -> Wt[N,K] bf16 ----------------
__global__ __launch_bounds__(256) void wtrans(const float* __restrict__ W,
                                              unsigned short* __restrict__ Wt,
                                              int K, int N){
  __shared__ float t[32][33];
  const int n0 = blockIdx.x * 32, k0 = blockIdx.y * 32;
  const int tx = threadIdx.x, ty = threadIdx.y;   // (32,8)
  #pragma unroll
  for (int i = 0; i < 4; i++)
    t[ty + i*8][tx] = W[(long)(k0 + ty + i*8) * N + n0 + tx];
  __syncthreads();
  #pragma unroll
  for (int i = 0; i < 4; i++)
    Wt[(long)(n0 + ty + i*8) * K + k0 + tx] = f2bf(t[tx][ty + i*8]);
}

// ---------------- LayerNorm over D=1024 rows: f32 in -> bf16 out ----------------
__global__ __launch_bounds__(256) void ln_rows(const float* __restrict__ in,
                                               const float* __restrict__ g,
                                               const float* __restrict__ beta,
                                               unsigned short* __restrict__ out){
  const long row = blockIdx.x;
  const int t = threadIdx.x;
  const float4 v = ((const float4*)(in + row * 1024))[t];
  float s  = v.x + v.y + v.z + v.w;
  float s2 = v.x*v.x + v.y*v.y + v.z*v.z + v.w*v.w;
  #pragma unroll
  for (int o = 32; o; o >>= 1){ s += __shfl_xor(s, o); s2 += __shfl_xor(s2, o); }
  __shared__ float rs[4], rq[4];
  const int wv = t >> 6;
  if ((t & 63) == 0){ rs[wv] = s; rq[wv] = s2; }
  __syncthreads();
  s  = rs[0] + rs[1] + rs[2] + rs[3];
  s2 = rq[0] + rq[1] + rq[2] + rq[3];
  const float mean = s * (1.f/1024.f);
  const float inv = rsqrtf(s2 * (1.f/1024.f) - mean*mean + 1e-6f);
  const float4 gv = ((const float4*)g)[t];
  const float4 bv = ((const float4*)beta)[t];
  ushort4 o4;
  o4.x = f2bf((v.x - mean)*inv*gv.x + bv.x);
  o4.y = f2bf((v.y - mean)*inv*gv.y + bv.y);
  o4.z = f2bf((v.z - mean)*inv*gv.z + bv.z);
  o4.w = f2bf((v.w - mean)*inv*gv.w + bv.w);
  *(ushort4*)(out + row * 1024 + t * 4) = o4;
}

// ---------------- per-head QK-LayerNorm prep ----------------
__global__ __launch_bounds__(256) void qkln(const float* __restrict__ qkvf,
    const float* __restrict__ qg, const float* __restrict__ qb,
    const float* __restrict__ kg, const float* __restrict__ kb,
    unsigned short* __restrict__ Qn, unsigned short* __restrict__ Kn){
  const int lane = threadIdx.x;                       // 64 = HD
  const int r = blockIdx.x * 4 + threadIdx.y;         // row in [0, 73728)
  const int bh = r / 576, p = r - bh * 576;
  const int b = bh >> 4, h = bh & 15;
  const long base = ((long)(b * 576 + p)) * 3072 + h * 64 + lane;
  float q = qkvf[base];
  float k = qkvf[base + 1024];
  float sq = q, sq2 = q*q, sk = k, sk2 = k*k;
  #pragma unroll
  for (int o = 32; o; o >>= 1){
    sq += __shfl_xor(sq, o); sq2 += __shfl_xor(sq2, o);
    sk += __shfl_xor(sk, o); sk2 += __shfl_xor(sk2, o);
  }
  const float mq = sq * (1.f/64.f), vq = sq2 * (1.f/64.f) - mq*mq;
  const float mk = sk * (1.f/64.f), vk = sk2 * (1.f/64.f) - mk*mk;
  const float qn = ((q - mq) * rsqrtf(vq + 1e-6f) * qg[lane] + qb[lane]) * 0.125f;
  const float kn =  (k - mk) * rsqrtf(vk + 1e-6f) * kg[lane] + kb[lane];
  const long ob = (long)r * 64 + lane;
  Qn[ob] = f2bf(qn);
  Kn[ob] = f2bf(kn);
}

// ---------------- V transpose per head ----------------
__global__ __launch_bounds__(256) void v_trans(const float* __restrict__ qkvf,
                                               unsigned short* __restrict__ Vt){
  const int bh = blockIdx.x, pt = blockIdx.y;
  const int b = bh >> 4, h = bh & 15;
  __shared__ float tile[64][65];
  const int t = threadIdx.x;
  #pragma unroll
  for (int i = 0; i < 16; i++){
    int idx = i * 256 + t; int p = idx >> 6, d = idx & 63;
    tile[p][d] = qkvf[((long)(b * 576) + pt * 64 + p) * 3072 + 2048 + h * 64 + d];
  }
  __syncthreads();
  #pragma unroll
  for (int i = 0; i < 16; i++){
    int idx = i * 256 + t; int d = idx >> 6, p = idx & 63;
    Vt[((long)bh * 64 + d) * 576 + pt * 64 + p] = f2bf(tile[p][d]);
  }
}

// ---------------- attention ----------------
__global__ __launch_bounds__(256) void attn_k(const unsigned short* __restrict__ Qn,
                                              const unsigned short* __restrict__ Kn,
                                              const unsigned short* __restrict__ Vt,
                                              float* __restrict__ O){
  const int qb = blockIdx.x;
  const int bh = blockIdx.y;
  const int b = bh >> 4, h = bh & 15;
  const int tid = threadIdx.x, wv = tid >> 6, lane = tid & 63;
  const int fr = lane & 15, fq = lane >> 4;
  __shared__ float S[16][578];
  __shared__ __align__(16) unsigned short Pl[16][584];

  const unsigned short* qbase = Qn + ((long)bh * 576 + qb * 16 + fr) * 64;
  frag8 qf0 = *(const frag8*)(qbase + fq * 8);
  frag8 qf1 = *(const frag8*)(qbase + 32 + fq * 8);

  for (int i = 0; i < 9; i++){
    const int kt = wv + 4 * i;
    const unsigned short* kbase = Kn + ((long)bh * 576 + kt * 16 + fr) * 64;
    frag8 kf0 = *(const frag8*)(kbase + fq * 8);
    frag8 kf1 = *(const frag8*)(kbase + 32 + fq * 8);
    accf4 a = {0.f, 0.f, 0.f, 0.f};
    a = __builtin_amdgcn_mfma_f32_16x16x32_bf16(qf0, kf0, a, 0, 0, 0);
    a = __builtin_amdgcn_mfma_f32_16x16x32_bf16(qf1, kf1, a, 0, 0, 0);
    #pragma unroll
    for (int rr = 0; rr < 4; rr++) S[fq * 4 + rr][kt * 16 + fr] = a[rr];
  }
  __syncthreads();

  {
    const int row = tid >> 4, cid = tid & 15;
    float vals[36];
    float mx = -1e30f;
    #pragma unroll
    for (int i = 0; i < 36; i++){ vals[i] = S[row][cid + 16 * i]; mx = fmaxf(mx, vals[i]); }
    #pragma unroll
    for (int o = 8; o; o >>= 1) mx = fmaxf(mx, __shfl_xor(mx, o));
    float sum = 0.f;
    #pragma unroll
    for (int i = 0; i < 36; i++){ vals[i] = __expf(vals[i] - mx); sum += vals[i]; }
    #pragma unroll
    for (int o = 8; o; o >>= 1) sum += __shfl_xor(sum, o);
    const float rsum = 1.f / sum;
    #pragma unroll
    for (int i = 0; i < 36; i++) Pl[row][cid + 16 * i] = f2bf(vals[i] * rsum);
  }
  __syncthreads();

  accf4 oa = {0.f, 0.f, 0.f, 0.f};
  for (int kt = 0; kt < 18; kt++){
    frag8 pf = *(const frag8*)&Pl[fr][kt * 32 + fq * 8];
    const unsigned short* vb = Vt + ((long)bh * 64 + wv * 16 + fr) * 576 + kt * 32 + fq * 8;
    frag8 vf = *(const frag8*)vb;
    oa = __builtin_amdgcn_mfma_f32_16x16x32_bf16(pf, vf, oa, 0, 0, 0);
  }
  #pragma unroll
  for (int rr = 0; rr < 4; rr++){
    const long orow = (long)b * 576 + qb * 16 + fq * 4 + rr;
    O[orow * 1024 + h * 64 + wv * 16 + fr] = oa[rr];
  }
}

// ---------------- 128x128 GEMM (2-phase), EPI 1: Cf = resid + (acc+bias)*ls ----------------
__global__ __launch_bounds__(256) void gemm_bt1(
    const unsigned short* __restrict__ A, const unsigned short* __restrict__ Bt,
    float* __restrict__ Cf,
    const float* __restrict__ bias, const float* __restrict__ ls,
    const float* __restrict__ resid, int M, int N, int K, int gx)
{
  __shared__ __align__(16) unsigned short As[128 * 32];
  __shared__ __align__(16) unsigned short Bs[128 * 32];
  const int tid = threadIdx.x;
  const int wave = tid >> 6, lane = tid & 63;
  const int fr = lane & 15, fq = lane >> 4;
  const int wr = wave >> 1, wc = wave & 1;
  // T1: XCD-aware bijective swizzle (nwg % 8 == 0 for all our launches)
  const int nwg = gridDim.x, bid = blockIdx.x;
  const int swz = ((nwg & 7) == 0) ? ((bid & 7) * (nwg >> 3) + (bid >> 3)) : bid;
  const int tx = swz % gx, ty = swz / gx;
  const long rowbase = (long)ty * 128;
  const long colbase = (long)tx * 128;

  accf4 acc[4][4];
  const accf4 zero = {0.f, 0.f, 0.f, 0.f};
  #pragma unroll
  for (int m = 0; m < 4; m++)
    #pragma unroll
    for (int n = 0; n < 4; n++) acc[m][n] = zero;

  const unsigned short* a0 = A + (rowbase + (tid >> 2)) * (long)K + (tid & 3) * 8;
  const unsigned short* a1 = a0 + 64l * K;
  const unsigned short* b0 = Bt + (colbase + (tid >> 2)) * (long)K + (tid & 3) * 8;
  const unsigned short* b1 = b0 + 64l * K;
  unsigned short* lA0 = &As[wave * 512];
  unsigned short* lA1 = &As[2048 + wave * 512];
  unsigned short* lB0 = &Bs[wave * 512];
  unsigned short* lB1 = &Bs[2048 + wave * 512];

  for (int k0 = 0; k0 < K; k0 += 32){
    __syncthreads();
    gload16(a0 + k0, lA0);
    gload16(a1 + k0, lA1);
    gload16(b0 + k0, lB0);
    gload16(b1 + k0, lB1);
    __syncthreads();
    frag8 af[4], bf[4];
    #pragma unroll
    for (int m = 0; m < 4; m++) af[m] = *(const frag8*)&As[(wr*64 + m*16 + fr)*32 + fq*8];
    #pragma unroll
    for (int n = 0; n < 4; n++) bf[n] = *(const frag8*)&Bs[(wc*64 + n*16 + fr)*32 + fq*8];
    #pragma unroll
    for (int m = 0; m < 4; m++)
      #pragma unroll
      for (int n = 0; n < 4; n++)
        acc[m][n] = __builtin_amdgcn_mfma_f32_16x16x32_bf16(af[m], bf[n], acc[m][n], 0, 0, 0);
  }

  #pragma unroll
  for (int m = 0; m < 4; m++){
    const long rb = rowbase + wr * 64 + m * 16 + fq * 4;
    #pragma unroll
    for (int n = 0; n < 4; n++){
      const long cb = colbase + wc * 64 + n * 16 + fr;
      #pragma unroll
      for (int r = 0; r < 4; r++){
        const long idx = (rb + r) * N + cb;
        Cf[idx] = resid[idx] + (acc[m][n][r] + bias[cb]) * ls[cb];
      }
    }
  }
}

// ---------------- 256x256 8-phase GEMM (T2+T3+T4+T5), bf16 in, f32 acc ----------------
// EPI 0: Cf = acc (f32).  EPI 2: Cb = bf16(gelu(acc + bias)).
// Schedule: BK=64 K-tiles; LDS double-buffer; chunks: A-mh (16KB), B-nh (16KB).
// Phase(mh,nh) order (0,0),(0,1),(1,0),(1,1); one half-tile staged per phase:
//   ph1: A1(u+1)->buf^1   ph2: B1(u+1)->buf^1   ph3: A0(u+2)->buf   ph4: B0(u+2)->buf
// Counted vmcnt(4) at ph4 only (in-flight: next tile's A0,B0). Drains at K-end.
// LDS swizzle: read col ^= (row&7)<<4; inverse applied on global source (dest linear).
template<int EPI>
__global__ __launch_bounds__(512) void gemm256(
    const unsigned short* __restrict__ Ag, const unsigned short* __restrict__ Btg,
    float* __restrict__ Cf, unsigned short* __restrict__ Cb,
    const float* __restrict__ bias, int M, int N, int K, int gx)
{
  __shared__ __align__(16) char lds[131072];   // A: [0,64K) B: [64K,128K)
  const int tid = threadIdx.x;
  const int w = tid >> 6, l = tid & 63;
  const int fr = l & 15, fq = l >> 4;
  const int wr = w >> 2, wc = w & 3;           // 2 x 4 waves
  const int fsw = (fr & 7) << 4;               // read-side swizzle

  // T1 swizzle (all launches have nwg % 8 == 0)
  const int nwg = gridDim.x, bid = blockIdx.x;
  const int swz = ((nwg & 7) == 0) ? ((bid & 7) * (nwg >> 3) + (bid >> 3)) : bid;
  const int tx = swz % gx, ty = swz / gx;
  const long rowbase = (long)ty * 256;
  const long colbase = (long)tx * 256;

  // staging per-thread constants
  const int j8 = l >> 3;                 // 0..7
  const int kg = (l & 7) ^ j8;           // inverse-swizzled k-group (16B units)
  const int r64_0 = (w*2 + 0)*8 + j8;    // row64 for load slot 0
  const int r64_1 = (w*2 + 1)*8 + j8;    // row64 for load slot 1
  const int NT = K >> 6;

  auto stageA = [&](int d, int mh, int t){
    const long k0 = (long)t * 64 + kg * 8;
    {
      const int r = ((r64_0 >> 6) << 7) + mh*64 + (r64_0 & 63);
      gload16(Ag + (rowbase + r) * (long)K + k0, lds + d*32768 + mh*16384 + (w*2+0)*1024);
    }
    {
      const int r = ((r64_1 >> 6) << 7) + mh*64 + (r64_1 & 63);
      gload16(Ag + (rowbase + r) * (long)K + k0, lds + d*32768 + mh*16384 + (w*2+1)*1024);
    }
  };
  auto stageB = [&](int d, int nh, int t){
    const long k0 = (long)t * 64 + kg * 8;
    {
      const int r = ((r64_0 >> 5) << 6) + nh*32 + (r64_0 & 31);
      gload16(Btg + (colbase + r) * (long)K + k0, lds + 65536 + d*32768 + nh*16384 + (w*2+0)*1024);
    }
    {
      const int r = ((r64_1 >> 5) << 6) + nh*32 + (r64_1 & 31);
      gload16(Btg + (colbase + r) * (long)K + k0, lds + 65536 + d*32768 + nh*16384 + (w*2+1)*1024);
    }
  };

  accf4 acc[8][4];
  const accf4 zero = {0.f, 0.f, 0.f, 0.f};
  #pragma unroll
  for (int m = 0; m < 8; m++)
    #pragma unroll
    for (int n = 0; n < 4; n++) acc[m][n] = zero;

  // ---- prologue: tile0 (4 chunks) + tile1 A0,B0 ----
  stageA(0, 0, 0); stageB(0, 0, 0); stageA(0, 1, 0); stageB(0, 1, 0);
  if (NT > 1){ stageA(1, 0, 1); stageB(1, 0, 1); }
  if (NT > 1){ asm volatile("s_waitcnt vmcnt(4)" ::: "memory"); }
  else       { asm volatile("s_waitcnt vmcnt(0)" ::: "memory"); }
  __builtin_amdgcn_s_barrier();
  __builtin_amdgcn_sched_barrier(0);

#define GPHASE(d, mh, nh, STAGES, WAITC)                                          \
  {                                                                               \
    frag8 af[4][2], bfr[2][2];                                                    \
    _Pragma("unroll")                                                             \
    for (int mi = 0; mi < 4; mi++)                                                \
      _Pragma("unroll")                                                           \
      for (int kk = 0; kk < 2; kk++)                                              \
        af[mi][kk] = *(const frag8*)(lds + (d)*32768 + (mh)*16384 +               \
            (wr*64 + mi*16 + fr)*128 + ((kk*64 + fq*16) ^ fsw));                  \
    _Pragma("unroll")                                                             \
    for (int nj = 0; nj < 2; nj++)                                                \
      _Pragma("unroll")                                                           \
      for (int kk = 0; kk < 2; kk++)                                              \
        bfr[nj][kk] = *(const frag8*)(lds + 65536 + (d)*32768 + (nh)*16384 +      \
            (wc*32 + nj*16 + fr)*128 + ((kk*64 + fq*16) ^ fsw));                  \
    STAGES;                                                                       \
    asm volatile("" ::: "memory");                                                \
    __builtin_amdgcn_s_barrier();                                                 \
    __builtin_amdgcn_sched_barrier(0);                                            \
    __builtin_amdgcn_s_setprio(1);                                                \
    _Pragma("unroll")                                                             \
    for (int mi = 0; mi < 4; mi++)                                                \
      _Pragma("unroll")                                                           \
      for (int nj = 0; nj < 2; nj++){                                             \
        acc[(mh)*4+mi][(nh)*2+nj] = __builtin_amdgcn_mfma_f32_16x16x32_bf16(      \
            af[mi][0], bfr[nj][0], acc[(mh)*4+mi][(nh)*2+nj], 0, 0, 0);           \
        acc[(mh)*4+mi][(nh)*2+nj] = __builtin_amdgcn_mfma_f32_16x16x32_bf16(      \
            af[mi][1], bfr[nj][1], acc[(mh)*4+mi][(nh)*2+nj], 0, 0, 0);           \
      }                                                                           \
    __builtin_amdgcn_s_setprio(0);                                                \
    __builtin_amdgcn_sched_barrier(0);                                            \
    WAITC;                                                                        \
    asm volatile("" ::: "memory");                                                \
    __builtin_amdgcn_s_barrier();                                                 \
    __builtin_amdgcn_sched_barrier(0);                                            \
  }

  for (int u = 0; u < NT; u += 2){
    // ---- tile u in buffer 0 ----
    GPHASE(0, 0, 0, { if (u+1 < NT) stageA(1, 1, u+1); }, {});
    GPHASE(0, 0, 1, { if (u+1 < NT) stageB(1, 1, u+1); }, {});
    GPHASE(0, 1, 0, { if (u+2 < NT) stageA(0, 0, u+2); }, {});
    GPHASE(0, 1, 1, { if (u+2 < NT) stageB(0, 0, u+2); },
           { if (u+2 < NT) asm volatile("s_waitcnt vmcnt(4)" ::: "memory");
             else          asm volatile("s_waitcnt vmcnt(0)" ::: "memory"); });
    // ---- tile u+1 in buffer 1 ----
    GPHASE(1, 0, 0, { if (u+2 < NT) stageA(0, 1, u+2); }, {});
    GPHASE(1, 0, 1, { if (u+2 < NT) stageB(0, 1, u+2); }, {});
    GPHASE(1, 1, 0, { if (u+3 < NT) stageA(1, 0, u+3); }, {});
    GPHASE(1, 1, 1, { if (u+3 < NT) stageB(1, 0, u+3); },
           { if (u+3 < NT) asm volatile("s_waitcnt vmcnt(4)" ::: "memory");
             else          asm volatile("s_waitcnt vmcnt(0)" ::: "memory"); });
  }
#undef GPHASE

  // ---- epilogue ----
  #pragma unroll
  for (int m = 0; m < 8; m++){
    const long rb = rowbase + wr*128 + m*16 + fq*4;
    #pragma unroll
    for (int n = 0; n < 4; n++){
      const long cb = colbase + wc*64 + n*16 + fr;
      #pragma unroll
      for (int r = 0; r < 4; r++){
        const long idx = (rb + r) * N + cb;
        if constexpr (EPI == 0){
          Cf[idx] = acc[m][n][r];
        } else {
          Cb[idx] = f2bf(gelu_tanh(acc[m][n][r] + bias[cb]));
        }
      }
    }
  }
}

extern "C" void kernel_launch(void* const* d_in, const int* in_sizes, int n_in,
                              void* d_out, int out_size, void* d_ws, size_t ws_size,
                              hipStream_t stream){
  (void)in_sizes; (void)n_in; (void)out_size; (void)ws_size;
  const float* x      = (const float*)d_in[0];
  const float* w_qkv  = (const float*)d_in[1];
  const float* q_g    = (const float*)d_in[2];
  const float* q_b    = (const float*)d_in[3];
  const float* k_g    = (const float*)d_in[4];
  const float* k_b    = (const float*)d_in[5];
  const float* o_g    = (const float*)d_in[6];
  const float* o_b    = (const float*)d_in[7];
  const float* w_proj = (const float*)d_in[8];
  const float* b_proj = (const float*)d_in[9];
  const float* ln1_g  = (const float*)d_in[10];
  const float* ln1_b  = (const float*)d_in[11];
  const float* ln2_g  = (const float*)d_in[12];
  const float* ln2_b  = (const float*)d_in[13];
  const float* w1     = (const float*)d_in[14];
  const float* b1     = (const float*)d_in[15];
  const float* w2     = (const float*)d_in[16];
  const float* b2     = (const float*)d_in[17];
  const float* ls1    = (const float*)d_in[18];
  const float* ls2    = (const float*)d_in[19];
  float* out = (float*)d_out;

  char* ws = (char*)d_ws;
  size_t off = 0;
  auto alloc = [&](size_t bytes)->void*{
    void* p = ws + off; off += (bytes + 255) & ~(size_t)255; return p;
  };
  unsigned short* wqkvT  = (unsigned short*)alloc(3072l*1024*2);
  unsigned short* wprojT = (unsigned short*)alloc(1024l*1024*2);
  unsigned short* w1T    = (unsigned short*)alloc(4096l*1024*2);
  unsigned short* w2T    = (unsigned short*)alloc(1024l*4096*2);
  unsigned short* xnA    = (unsigned short*)alloc(4608l*1024*2);
  float*          qkvf   = (float*)alloc(4608l*3072*4);
  unsigned short* Qn     = (unsigned short*)alloc(73728l*64*2);
  unsigned short* Kn     = (unsigned short*)alloc(73728l*64*2);
  unsigned short* Vt     = (unsigned short*)alloc(73728l*64*2);
  float*          attnO  = qkvf;
  unsigned short* hbf    = (unsigned short*)((char*)qkvf + 4608l*1024*4);

  // weights -> bf16 B^T
  wtrans<<<dim3(3072/32, 1024/32), dim3(32,8), 0, stream>>>(w_qkv,  wqkvT,  1024, 3072);
  wtrans<<<dim3(1024/32, 1024/32), dim3(32,8), 0, stream>>>(w_proj, wprojT, 1024, 1024);
  wtrans<<<dim3(4096/32, 1024/32), dim3(32,8), 0, stream>>>(w1,     w1T,    1024, 4096);
  wtrans<<<dim3(1024/32, 4096/32), dim3(32,8), 0, stream>>>(w2,     w2T,    4096, 1024);

  // attention branch
  ln_rows<<<4608, 256, 0, stream>>>(x, ln1_g, ln1_b, xnA);
  gemm256<0><<<12*18, 512, 0, stream>>>(xnA, wqkvT, qkvf, nullptr, nullptr,
                                        4608, 3072, 1024, 12);
  qkln<<<18432, dim3(64,4), 0, stream>>>(qkvf, q_g, q_b, k_g, k_b, Qn, Kn);
  v_trans<<<dim3(128,9), 256, 0, stream>>>(qkvf, Vt);
  attn_k<<<dim3(36,128), 256, 0, stream>>>(Qn, Kn, Vt, attnO);
  ln_rows<<<4608, 256, 0, stream>>>(attnO, o_g, o_b, xnA);
  gemm_bt1<<<8*36, 256, 0, stream>>>(xnA, wprojT, out, b_proj, ls1, x,
                                     4608, 1024, 1024, 8);
  // MLP branch
  ln_rows<<<4608, 256, 0, stream>>>(out, ln2_g, ln2_b, xnA);
  gemm256<2><<<16*18, 512, 0, stream>>>(xnA, w1T, nullptr, hbf, b1,
                                        4608, 4096, 1024, 16);
  gemm_bt1<<<8*36, 256, 0, stream>>>(hbf, w2T, out, b2, ls2, out,
                                     4608, 1024, 4096, 8);
}

// Round 6
// 372.669 us; speedup vs baseline: 1.0520x; 1.0520x over previous
//
#include <hip/hip_runtime.h>
#include <hip/hip_bf16.h>

#define DEV static __device__ __forceinline__

typedef short frag8 __attribute__((ext_vector_type(8)));
typedef float accf4 __attribute__((ext_vector_type(4)));

// Problem constants: B=8, P=576, D=1024, H=16, HD=64, HID=4096, BP=4608, BH=128

DEV unsigned short f2bf(float f){
  union { float f; unsigned int u; } v; v.f = f;
  unsigned int r = v.u + 0x7fffu + ((v.u >> 16) & 1u);
  return (unsigned short)(r >> 16);
}

DEV void gload16(const void* g, void* l){
  __builtin_amdgcn_global_load_lds((const __attribute__((address_space(1))) void*)g,
                                   (__attribute__((address_space(3))) void*)l, 16, 0, 0);
}

DEV float gelu_tanh(float x){
  float u = 0.7978845608028654f * (x + 0.044715f * x * x * x);
  float e = __expf(2.0f * u);
  float th = 1.0f - 2.0f / (e + 1.0f);   // tanh(u), inf-safe
  return 0.5f * x * (1.0f + th);
}

// ---------------- weight cast + transpose: W[K,N] f32 -> Wt[N,K] bf16 ----------------
__global__ __launch_bounds__(256) void wtrans(const float* __restrict__ W,
                                              unsigned short* __restrict__ Wt,
                                              int K, int N){
  __shared__ float t[32][33];
  const int n0 = blockIdx.x * 32, k0 = blockIdx.y * 32;
  const int tx = threadIdx.x, ty = threadIdx.y;   // (32,8)
  #pragma unroll
  for (int i = 0; i < 4; i++)
    t[ty + i*8][tx] = W[(long)(k0 + ty + i*8) * N + n0 + tx];
  __syncthreads();
  #pragma unroll
  for (int i = 0; i < 4; i++)
    Wt[(long)(n0 + ty + i*8) * K + k0 + tx] = f2bf(t[tx][ty + i*8]);
}

// ---------------- LayerNorm over D=1024 rows: f32 in -> bf16 out ----------------
__global__ __launch_bounds__(256) void ln_rows(const float* __restrict__ in,
                                               const float* __restrict__ g,
                                               const float* __restrict__ beta,
                                               unsigned short* __restrict__ out){
  const long row = blockIdx.x;
  const int t = threadIdx.x;
  const float4 v = ((const float4*)(in + row * 1024))[t];
  float s  = v.x + v.y + v.z + v.w;
  float s2 = v.x*v.x + v.y*v.y + v.z*v.z + v.w*v.w;
  #pragma unroll
  for (int o = 32; o; o >>= 1){ s += __shfl_xor(s, o); s2 += __shfl_xor(s2, o); }
  __shared__ float rs[4], rq[4];
  const int wv = t >> 6;
  if ((t & 63) == 0){ rs[wv] = s; rq[wv] = s2; }
  __syncthreads();
  s  = rs[0] + rs[1] + rs[2] + rs[3];
  s2 = rq[0] + rq[1] + rq[2] + rq[3];
  const float mean = s * (1.f/1024.f);
  const float inv = rsqrtf(s2 * (1.f/1024.f) - mean*mean + 1e-6f);
  const float4 gv = ((const float4*)g)[t];
  const float4 bv = ((const float4*)beta)[t];
  ushort4 o4;
  o4.x = f2bf((v.x - mean)*inv*gv.x + bv.x);
  o4.y = f2bf((v.y - mean)*inv*gv.y + bv.y);
  o4.z = f2bf((v.z - mean)*inv*gv.z + bv.z);
  o4.w = f2bf((v.w - mean)*inv*gv.w + bv.w);
  *(ushort4*)(out + row * 1024 + t * 4) = o4;
}

// ---------------- V transpose per head: qkvVf [4608][1024] f32 -> Vt [BH][64][576] bf16 ----------------
__global__ __launch_bounds__(256) void v_trans(const float* __restrict__ qkvVf,
                                               unsigned short* __restrict__ Vt){
  const int bh = blockIdx.x, pt = blockIdx.y;   // pt: 0..8 (64 p's each)
  const int b = bh >> 4, h = bh & 15;
  __shared__ float tile[64][65];
  const int t = threadIdx.x;
  #pragma unroll
  for (int i = 0; i < 16; i++){
    int idx = i * 256 + t; int p = idx >> 6, d = idx & 63;
    tile[p][d] = qkvVf[((long)(b * 576) + pt * 64 + p) * 1024 + h * 64 + d];
  }
  __syncthreads();
  #pragma unroll
  for (int i = 0; i < 16; i++){
    int idx = i * 256 + t; int d = idx >> 6, p = idx & 63;
    Vt[((long)bh * 64 + d) * 576 + pt * 64 + p] = f2bf(tile[p][d]);
  }
}

// ---------------- attention: one block = one (bh, 16-q-row tile) ----------------
__global__ __launch_bounds__(256) void attn_k(const unsigned short* __restrict__ Qn,
                                              const unsigned short* __restrict__ Kn,
                                              const unsigned short* __restrict__ Vt,
                                              float* __restrict__ O){
  const int qb = blockIdx.x;
  const int bh = blockIdx.y;
  const int b = bh >> 4, h = bh & 15;
  const int tid = threadIdx.x, wv = tid >> 6, lane = tid & 63;
  const int fr = lane & 15, fq = lane >> 4;
  __shared__ float S[16][578];
  __shared__ __align__(16) unsigned short Pl[16][584];

  const unsigned short* qbase = Qn + ((long)bh * 576 + qb * 16 + fr) * 64;
  frag8 qf0 = *(const frag8*)(qbase + fq * 8);
  frag8 qf1 = *(const frag8*)(qbase + 32 + fq * 8);

  for (int i = 0; i < 9; i++){
    const int kt = wv + 4 * i;
    const unsigned short* kbase = Kn + ((long)bh * 576 + kt * 16 + fr) * 64;
    frag8 kf0 = *(const frag8*)(kbase + fq * 8);
    frag8 kf1 = *(const frag8*)(kbase + 32 + fq * 8);
    accf4 a = {0.f, 0.f, 0.f, 0.f};
    a = __builtin_amdgcn_mfma_f32_16x16x32_bf16(qf0, kf0, a, 0, 0, 0);
    a = __builtin_amdgcn_mfma_f32_16x16x32_bf16(qf1, kf1, a, 0, 0, 0);
    #pragma unroll
    for (int rr = 0; rr < 4; rr++) S[fq * 4 + rr][kt * 16 + fr] = a[rr];
  }
  __syncthreads();

  {
    const int row = tid >> 4, cid = tid & 15;
    float vals[36];
    float mx = -1e30f;
    #pragma unroll
    for (int i = 0; i < 36; i++){ vals[i] = S[row][cid + 16 * i]; mx = fmaxf(mx, vals[i]); }
    #pragma unroll
    for (int o = 8; o; o >>= 1) mx = fmaxf(mx, __shfl_xor(mx, o));
    float sum = 0.f;
    #pragma unroll
    for (int i = 0; i < 36; i++){ vals[i] = __expf(vals[i] - mx); sum += vals[i]; }
    #pragma unroll
    for (int o = 8; o; o >>= 1) sum += __shfl_xor(sum, o);
    const float rsum = 1.f / sum;
    #pragma unroll
    for (int i = 0; i < 36; i++) Pl[row][cid + 16 * i] = f2bf(vals[i] * rsum);
  }
  __syncthreads();

  accf4 oa = {0.f, 0.f, 0.f, 0.f};
  for (int kt = 0; kt < 18; kt++){
    frag8 pf = *(const frag8*)&Pl[fr][kt * 32 + fq * 8];
    const unsigned short* vb = Vt + ((long)bh * 64 + wv * 16 + fr) * 576 + kt * 32 + fq * 8;
    frag8 vf = *(const frag8*)vb;
    oa = __builtin_amdgcn_mfma_f32_16x16x32_bf16(pf, vf, oa, 0, 0, 0);
  }
  #pragma unroll
  for (int rr = 0; rr < 4; rr++){
    const long orow = (long)b * 576 + qb * 16 + fq * 4 + rr;
    O[orow * 1024 + h * 64 + wv * 16 + fr] = oa[rr];
  }
}

// ---------------- 128x128 2-phase GEMM + T1, fused epilogues ----------------
// EPI 1: Cf = resid + (acc+bias)*ls (f32).
// EPI 2: Cb = bf16(gelu(acc+bias)).
// EPI 3: QKV — per-head QK-LayerNorm fused (Q scaled 0.125) -> Qn/Kn bf16; V -> Vf f32.
template<int EPI>
__global__ __launch_bounds__(256) void gemm_bt(
    const unsigned short* __restrict__ A, const unsigned short* __restrict__ Bt,
    float* __restrict__ Cf, unsigned short* __restrict__ Cb,
    const float* __restrict__ bias, const float* __restrict__ ls,
    const float* __restrict__ resid,
    const float* __restrict__ qg, const float* __restrict__ qb2,
    const float* __restrict__ kg, const float* __restrict__ kb2,
    unsigned short* __restrict__ Qn, unsigned short* __restrict__ Kn,
    float* __restrict__ Vf,
    int M, int N, int K, int gx)
{
  __shared__ __align__(16) unsigned short As[128 * 32];
  __shared__ __align__(16) unsigned short Bs[128 * 32];
  const int tid = threadIdx.x;
  const int wave = tid >> 6, lane = tid & 63;
  const int fr = lane & 15, fq = lane >> 4;
  const int wr = wave >> 1, wc = wave & 1;
  // T1: XCD-aware bijective swizzle (all launches have nwg % 8 == 0)
  const int nwg = gridDim.x, bid = blockIdx.x;
  const int swz = ((nwg & 7) == 0) ? ((bid & 7) * (nwg >> 3) + (bid >> 3)) : bid;
  const int tx = swz % gx, ty = swz / gx;
  const long rowbase = (long)ty * 128;
  const long colbase = (long)tx * 128;

  accf4 acc[4][4];
  const accf4 zero = {0.f, 0.f, 0.f, 0.f};
  #pragma unroll
  for (int m = 0; m < 4; m++)
    #pragma unroll
    for (int n = 0; n < 4; n++) acc[m][n] = zero;

  const unsigned short* a0 = A + (rowbase + (tid >> 2)) * (long)K + (tid & 3) * 8;
  const unsigned short* a1 = a0 + 64l * K;
  const unsigned short* b0 = Bt + (colbase + (tid >> 2)) * (long)K + (tid & 3) * 8;
  const unsigned short* b1 = b0 + 64l * K;
  unsigned short* lA0 = &As[wave * 512];
  unsigned short* lA1 = &As[2048 + wave * 512];
  unsigned short* lB0 = &Bs[wave * 512];
  unsigned short* lB1 = &Bs[2048 + wave * 512];

  for (int k0 = 0; k0 < K; k0 += 32){
    __syncthreads();
    gload16(a0 + k0, lA0);
    gload16(a1 + k0, lA1);
    gload16(b0 + k0, lB0);
    gload16(b1 + k0, lB1);
    __syncthreads();
    frag8 af[4], bf[4];
    #pragma unroll
    for (int m = 0; m < 4; m++) af[m] = *(const frag8*)&As[(wr*64 + m*16 + fr)*32 + fq*8];
    #pragma unroll
    for (int n = 0; n < 4; n++) bf[n] = *(const frag8*)&Bs[(wc*64 + n*16 + fr)*32 + fq*8];
    #pragma unroll
    for (int m = 0; m < 4; m++)
      #pragma unroll
      for (int n = 0; n < 4; n++)
        acc[m][n] = __builtin_amdgcn_mfma_f32_16x16x32_bf16(af[m], bf[n], acc[m][n], 0, 0, 0);
  }

  if constexpr (EPI == 3){
    // wave owns a 64-row x 64-col tile; 64-col group = one head of one kind
    const int cg = (int)colbase + wc * 64;       // multiple of 64
    const int kind = cg >> 10;                   // 0=Q, 1=K, 2=V
    const int h = (cg & 1023) >> 6;
    if (kind < 2){
      const float* g  = kind ? kg : qg;
      const float* bb = kind ? kb2 : qb2;
      const float sc = kind ? 1.0f : 0.125f;
      unsigned short* Out = kind ? Kn : Qn;
      #pragma unroll
      for (int m = 0; m < 4; m++){
        #pragma unroll
        for (int r = 0; r < 4; r++){
          float s1 = 0.f, s2 = 0.f;
          #pragma unroll
          for (int n = 0; n < 4; n++){ const float v = acc[m][n][r]; s1 += v; s2 += v*v; }
          #pragma unroll
          for (int o = 8; o; o >>= 1){ s1 += __shfl_xor(s1, o); s2 += __shfl_xor(s2, o); }
          const float mean = s1 * (1.f/64.f);
          const float inv = rsqrtf(s2 * (1.f/64.f) - mean*mean + 1e-6f);
          const long row = rowbase + wr*64 + m*16 + fq*4 + r;
          const int bq = (int)(row / 576), p = (int)(row - (long)bq*576);
          unsigned short* dst = Out + (((long)(bq*16 + h))*576 + p)*64;
          #pragma unroll
          for (int n = 0; n < 4; n++){
            const int d = n*16 + fr;
            dst[d] = f2bf(((acc[m][n][r] - mean)*inv*g[d] + bb[d]) * sc);
          }
        }
      }
    } else {
      // V third: plain f32 into Vf [4608][1024] at col (cg-2048)+...
      #pragma unroll
      for (int m = 0; m < 4; m++){
        const long rb = rowbase + wr*64 + m*16 + fq*4;
        #pragma unroll
        for (int n = 0; n < 4; n++){
          const int vc = (cg - 2048) + n*16 + fr;
          #pragma unroll
          for (int r = 0; r < 4; r++)
            Vf[(rb + r)*1024 + vc] = acc[m][n][r];
        }
      }
    }
  } else {
    #pragma unroll
    for (int m = 0; m < 4; m++){
      const long rb = rowbase + wr * 64 + m * 16 + fq * 4;
      #pragma unroll
      for (int n = 0; n < 4; n++){
        const long cb = colbase + wc * 64 + n * 16 + fr;
        #pragma unroll
        for (int r = 0; r < 4; r++){
          const long idx = (rb + r) * N + cb;
          const float v = acc[m][n][r];
          if constexpr (EPI == 1){
            Cf[idx] = resid[idx] + (v + bias[cb]) * ls[cb];
          } else {
            Cb[idx] = f2bf(gelu_tanh(v + bias[cb]));
          }
        }
      }
    }
  }
}

extern "C" void kernel_launch(void* const* d_in, const int* in_sizes, int n_in,
                              void* d_out, int out_size, void* d_ws, size_t ws_size,
                              hipStream_t stream){
  (void)in_sizes; (void)n_in; (void)out_size; (void)ws_size;
  const float* x      = (const float*)d_in[0];
  const float* w_qkv  = (const float*)d_in[1];
  const float* q_g    = (const float*)d_in[2];
  const float* q_b    = (const float*)d_in[3];
  const float* k_g    = (const float*)d_in[4];
  const float* k_b    = (const float*)d_in[5];
  const float* o_g    = (const float*)d_in[6];
  const float* o_b    = (const float*)d_in[7];
  const float* w_proj = (const float*)d_in[8];
  const float* b_proj = (const float*)d_in[9];
  const float* ln1_g  = (const float*)d_in[10];
  const float* ln1_b  = (const float*)d_in[11];
  const float* ln2_g  = (const float*)d_in[12];
  const float* ln2_b  = (const float*)d_in[13];
  const float* w1     = (const float*)d_in[14];
  const float* b1     = (const float*)d_in[15];
  const float* w2     = (const float*)d_in[16];
  const float* b2     = (const float*)d_in[17];
  const float* ls1    = (const float*)d_in[18];
  const float* ls2    = (const float*)d_in[19];
  float* out = (float*)d_out;

  char* ws = (char*)d_ws;
  size_t off = 0;
  auto alloc = [&](size_t bytes)->void*{
    void* p = ws + off; off += (bytes + 255) & ~(size_t)255; return p;
  };
  unsigned short* wqkvT  = (unsigned short*)alloc(3072l*1024*2);
  unsigned short* wprojT = (unsigned short*)alloc(1024l*1024*2);
  unsigned short* w1T    = (unsigned short*)alloc(4096l*1024*2);
  unsigned short* w2T    = (unsigned short*)alloc(1024l*4096*2);
  unsigned short* xnA    = (unsigned short*)alloc(4608l*1024*2);   // xn1 / on / xn2
  float*          qkvVf  = (float*)alloc(4608l*1024*4);            // V third, f32
  unsigned short* Qn     = (unsigned short*)alloc(73728l*64*2);
  unsigned short* Kn     = (unsigned short*)alloc(73728l*64*2);
  unsigned short* Vt     = (unsigned short*)alloc(73728l*64*2);
  unsigned short* hbf    = (unsigned short*)alloc(4608l*4096*2);
  float*          attnO  = qkvVf;   // overlay: qkvVf dead after v_trans

  // weights -> bf16 B^T
  wtrans<<<dim3(3072/32, 1024/32), dim3(32,8), 0, stream>>>(w_qkv,  wqkvT,  1024, 3072);
  wtrans<<<dim3(1024/32, 1024/32), dim3(32,8), 0, stream>>>(w_proj, wprojT, 1024, 1024);
  wtrans<<<dim3(4096/32, 1024/32), dim3(32,8), 0, stream>>>(w1,     w1T,    1024, 4096);
  wtrans<<<dim3(1024/32, 4096/32), dim3(32,8), 0, stream>>>(w2,     w2T,    4096, 1024);

  // attention branch
  ln_rows<<<4608, 256, 0, stream>>>(x, ln1_g, ln1_b, xnA);
  gemm_bt<3><<<24*36, 256, 0, stream>>>(xnA, wqkvT, nullptr, nullptr,
                                        nullptr, nullptr, nullptr,
                                        q_g, q_b, k_g, k_b, Qn, Kn, qkvVf,
                                        4608, 3072, 1024, 24);
  v_trans<<<dim3(128,9), 256, 0, stream>>>(qkvVf, Vt);
  attn_k<<<dim3(36,128), 256, 0, stream>>>(Qn, Kn, Vt, attnO);
  ln_rows<<<4608, 256, 0, stream>>>(attnO, o_g, o_b, xnA);
  gemm_bt<1><<<8*36, 256, 0, stream>>>(xnA, wprojT, out, nullptr,
                                       b_proj, ls1, x,
                                       nullptr, nullptr, nullptr, nullptr,
                                       nullptr, nullptr, nullptr,
                                       4608, 1024, 1024, 8);
  // MLP branch
  ln_rows<<<4608, 256, 0, stream>>>(out, ln2_g, ln2_b, xnA);
  gemm_bt<2><<<32*36, 256, 0, stream>>>(xnA, w1T, nullptr, hbf,
                                        b1, nullptr, nullptr,
                                        nullptr, nullptr, nullptr, nullptr,
                                        nullptr, nullptr, nullptr,
                                        4608, 4096, 1024, 32);
  gemm_bt<1><<<8*36, 256, 0, stream>>>(hbf, w2T, out, nullptr,
                                       b2, ls2, out,
                                       nullptr, nullptr, nullptr, nullptr,
                                       nullptr, nullptr, nullptr,
                                       4608, 1024, 4096, 8);
}

// Round 7
// 357.956 us; speedup vs baseline: 1.0952x; 1.0411x over previous
//
#include <hip/hip_runtime.h>
#include <hip/hip_bf16.h>

#define DEV static __device__ __forceinline__

typedef short frag8 __attribute__((ext_vector_type(8)));
typedef float accf4 __attribute__((ext_vector_type(4)));

// Problem constants: B=8, P=576, D=1024, H=16, HD=64, HID=4096, BP=4608, BH=128

DEV unsigned short f2bf(float f){
  union { float f; unsigned int u; } v; v.f = f;
  unsigned int r = v.u + 0x7fffu + ((v.u >> 16) & 1u);
  return (unsigned short)(r >> 16);
}

DEV void gload16(const void* g, void* l){
  __builtin_amdgcn_global_load_lds((const __attribute__((address_space(1))) void*)g,
                                   (__attribute__((address_space(3))) void*)l, 16, 0, 0);
}

DEV float gelu_tanh(float x){
  float u = 0.7978845608028654f * (x + 0.044715f * x * x * x);
  float e = __expf(2.0f * u);
  float th = 1.0f - 2.0f / (e + 1.0f);   // tanh(u), inf-safe
  return 0.5f * x * (1.0f + th);
}

// ---------------- weight cast + transpose: W[K,N] f32 -> Wt[N,K] bf16 ----------------
__global__ __launch_bounds__(256) void wtrans(const float* __restrict__ W,
                                              unsigned short* __restrict__ Wt,
                                              int K, int N){
  __shared__ float t[32][33];
  const int n0 = blockIdx.x * 32, k0 = blockIdx.y * 32;
  const int tx = threadIdx.x, ty = threadIdx.y;   // (32,8)
  #pragma unroll
  for (int i = 0; i < 4; i++)
    t[ty + i*8][tx] = W[(long)(k0 + ty + i*8) * N + n0 + tx];
  __syncthreads();
  #pragma unroll
  for (int i = 0; i < 4; i++)
    Wt[(long)(n0 + ty + i*8) * K + k0 + tx] = f2bf(t[tx][ty + i*8]);
}

// ---------------- LayerNorm over D=1024 rows: f32 in -> bf16 out ----------------
__global__ __launch_bounds__(256) void ln_rows(const float* __restrict__ in,
                                               const float* __restrict__ g,
                                               const float* __restrict__ beta,
                                               unsigned short* __restrict__ out){
  const long row = blockIdx.x;
  const int t = threadIdx.x;
  const float4 v = ((const float4*)(in + row * 1024))[t];
  float s  = v.x + v.y + v.z + v.w;
  float s2 = v.x*v.x + v.y*v.y + v.z*v.z + v.w*v.w;
  #pragma unroll
  for (int o = 32; o; o >>= 1){ s += __shfl_xor(s, o); s2 += __shfl_xor(s2, o); }
  __shared__ float rs[4], rq[4];
  const int wv = t >> 6;
  if ((t & 63) == 0){ rs[wv] = s; rq[wv] = s2; }
  __syncthreads();
  s  = rs[0] + rs[1] + rs[2] + rs[3];
  s2 = rq[0] + rq[1] + rq[2] + rq[3];
  const float mean = s * (1.f/1024.f);
  const float inv = rsqrtf(s2 * (1.f/1024.f) - mean*mean + 1e-6f);
  const float4 gv = ((const float4*)g)[t];
  const float4 bv = ((const float4*)beta)[t];
  ushort4 o4;
  o4.x = f2bf((v.x - mean)*inv*gv.x + bv.x);
  o4.y = f2bf((v.y - mean)*inv*gv.y + bv.y);
  o4.z = f2bf((v.z - mean)*inv*gv.z + bv.z);
  o4.w = f2bf((v.w - mean)*inv*gv.w + bv.w);
  *(ushort4*)(out + row * 1024 + t * 4) = o4;
}

// ---------------- V transpose per head: qkvVf [4608][1024] f32 -> Vt [BH][64][576] bf16 ----------------
__global__ __launch_bounds__(256) void v_trans(const float* __restrict__ qkvVf,
                                               unsigned short* __restrict__ Vt){
  const int bh = blockIdx.x, pt = blockIdx.y;   // pt: 0..8 (64 p's each)
  const int b = bh >> 4, h = bh & 15;
  __shared__ float tile[64][65];
  const int t = threadIdx.x;
  #pragma unroll
  for (int i = 0; i < 16; i++){
    int idx = i * 256 + t; int p = idx >> 6, d = idx & 63;
    tile[p][d] = qkvVf[((long)(b * 576) + pt * 64 + p) * 1024 + h * 64 + d];
  }
  __syncthreads();
  #pragma unroll
  for (int i = 0; i < 16; i++){
    int idx = i * 256 + t; int d = idx >> 6, p = idx & 63;
    Vt[((long)bh * 64 + d) * 576 + pt * 64 + p] = f2bf(tile[p][d]);
  }
}

// ---------------- attention: one block = one (bh, 16-q-row tile) ----------------
__global__ __launch_bounds__(256) void attn_k(const unsigned short* __restrict__ Qn,
                                              const unsigned short* __restrict__ Kn,
                                              const unsigned short* __restrict__ Vt,
                                              float* __restrict__ O){
  const int qb = blockIdx.x;
  const int bh = blockIdx.y;
  const int b = bh >> 4, h = bh & 15;
  const int tid = threadIdx.x, wv = tid >> 6, lane = tid & 63;
  const int fr = lane & 15, fq = lane >> 4;
  __shared__ float S[16][578];
  __shared__ __align__(16) unsigned short Pl[16][584];

  const unsigned short* qbase = Qn + ((long)bh * 576 + qb * 16 + fr) * 64;
  frag8 qf0 = *(const frag8*)(qbase + fq * 8);
  frag8 qf1 = *(const frag8*)(qbase + 32 + fq * 8);

  for (int i = 0; i < 9; i++){
    const int kt = wv + 4 * i;
    const unsigned short* kbase = Kn + ((long)bh * 576 + kt * 16 + fr) * 64;
    frag8 kf0 = *(const frag8*)(kbase + fq * 8);
    frag8 kf1 = *(const frag8*)(kbase + 32 + fq * 8);
    accf4 a = {0.f, 0.f, 0.f, 0.f};
    a = __builtin_amdgcn_mfma_f32_16x16x32_bf16(qf0, kf0, a, 0, 0, 0);
    a = __builtin_amdgcn_mfma_f32_16x16x32_bf16(qf1, kf1, a, 0, 0, 0);
    #pragma unroll
    for (int rr = 0; rr < 4; rr++) S[fq * 4 + rr][kt * 16 + fr] = a[rr];
  }
  __syncthreads();

  {
    const int row = tid >> 4, cid = tid & 15;
    float vals[36];
    float mx = -1e30f;
    #pragma unroll
    for (int i = 0; i < 36; i++){ vals[i] = S[row][cid + 16 * i]; mx = fmaxf(mx, vals[i]); }
    #pragma unroll
    for (int o = 8; o; o >>= 1) mx = fmaxf(mx, __shfl_xor(mx, o));
    float sum = 0.f;
    #pragma unroll
    for (int i = 0; i < 36; i++){ vals[i] = __expf(vals[i] - mx); sum += vals[i]; }
    #pragma unroll
    for (int o = 8; o; o >>= 1) sum += __shfl_xor(sum, o);
    const float rsum = 1.f / sum;
    #pragma unroll
    for (int i = 0; i < 36; i++) Pl[row][cid + 16 * i] = f2bf(vals[i] * rsum);
  }
  __syncthreads();

  accf4 oa = {0.f, 0.f, 0.f, 0.f};
  for (int kt = 0; kt < 18; kt++){
    frag8 pf = *(const frag8*)&Pl[fr][kt * 32 + fq * 8];
    const unsigned short* vb = Vt + ((long)bh * 64 + wv * 16 + fr) * 576 + kt * 32 + fq * 8;
    frag8 vf = *(const frag8*)vb;
    oa = __builtin_amdgcn_mfma_f32_16x16x32_bf16(pf, vf, oa, 0, 0, 0);
  }
  #pragma unroll
  for (int rr = 0; rr < 4; rr++){
    const long orow = (long)b * 576 + qb * 16 + fq * 4 + rr;
    O[orow * 1024 + h * 64 + wv * 16 + fr] = oa[rr];
  }
}

// ---------------- 128x128 2-phase GEMM + T1, fused epilogues ----------------
// EPI 2: Cb = bf16(gelu(acc+bias)).
// EPI 3: QKV — per-head QK-LayerNorm fused (Q scaled 0.125) -> Qn/Kn bf16; V -> Vf f32.
template<int EPI>
__global__ __launch_bounds__(256) void gemm_bt(
    const unsigned short* __restrict__ A, const unsigned short* __restrict__ Bt,
    float* __restrict__ Cf, unsigned short* __restrict__ Cb,
    const float* __restrict__ bias, const float* __restrict__ ls,
    const float* __restrict__ resid,
    const float* __restrict__ qg, const float* __restrict__ qb2,
    const float* __restrict__ kg, const float* __restrict__ kb2,
    unsigned short* __restrict__ Qn, unsigned short* __restrict__ Kn,
    float* __restrict__ Vf,
    int M, int N, int K, int gx)
{
  __shared__ __align__(16) unsigned short As[128 * 32];
  __shared__ __align__(16) unsigned short Bs[128 * 32];
  const int tid = threadIdx.x;
  const int wave = tid >> 6, lane = tid & 63;
  const int fr = lane & 15, fq = lane >> 4;
  const int wr = wave >> 1, wc = wave & 1;
  // T1: XCD-aware bijective swizzle (all launches have nwg % 8 == 0)
  const int nwg = gridDim.x, bid = blockIdx.x;
  const int swz = ((nwg & 7) == 0) ? ((bid & 7) * (nwg >> 3) + (bid >> 3)) : bid;
  const int tx = swz % gx, ty = swz / gx;
  const long rowbase = (long)ty * 128;
  const long colbase = (long)tx * 128;

  accf4 acc[4][4];
  const accf4 zero = {0.f, 0.f, 0.f, 0.f};
  #pragma unroll
  for (int m = 0; m < 4; m++)
    #pragma unroll
    for (int n = 0; n < 4; n++) acc[m][n] = zero;

  const unsigned short* a0 = A + (rowbase + (tid >> 2)) * (long)K + (tid & 3) * 8;
  const unsigned short* a1 = a0 + 64l * K;
  const unsigned short* b0 = Bt + (colbase + (tid >> 2)) * (long)K + (tid & 3) * 8;
  const unsigned short* b1 = b0 + 64l * K;
  unsigned short* lA0 = &As[wave * 512];
  unsigned short* lA1 = &As[2048 + wave * 512];
  unsigned short* lB0 = &Bs[wave * 512];
  unsigned short* lB1 = &Bs[2048 + wave * 512];

  for (int k0 = 0; k0 < K; k0 += 32){
    __syncthreads();
    gload16(a0 + k0, lA0);
    gload16(a1 + k0, lA1);
    gload16(b0 + k0, lB0);
    gload16(b1 + k0, lB1);
    __syncthreads();
    frag8 af[4], bf[4];
    #pragma unroll
    for (int m = 0; m < 4; m++) af[m] = *(const frag8*)&As[(wr*64 + m*16 + fr)*32 + fq*8];
    #pragma unroll
    for (int n = 0; n < 4; n++) bf[n] = *(const frag8*)&Bs[(wc*64 + n*16 + fr)*32 + fq*8];
    #pragma unroll
    for (int m = 0; m < 4; m++)
      #pragma unroll
      for (int n = 0; n < 4; n++)
        acc[m][n] = __builtin_amdgcn_mfma_f32_16x16x32_bf16(af[m], bf[n], acc[m][n], 0, 0, 0);
  }

  if constexpr (EPI == 3){
    // wave owns a 64-row x 64-col tile; 64-col group = one head of one kind
    const int cg = (int)colbase + wc * 64;       // multiple of 64
    const int kind = cg >> 10;                   // 0=Q, 1=K, 2=V
    const int h = (cg & 1023) >> 6;
    if (kind < 2){
      const float* g  = kind ? kg : qg;
      const float* bb = kind ? kb2 : qb2;
      const float sc = kind ? 1.0f : 0.125f;
      unsigned short* Out = kind ? Kn : Qn;
      #pragma unroll
      for (int m = 0; m < 4; m++){
        #pragma unroll
        for (int r = 0; r < 4; r++){
          float s1 = 0.f, s2 = 0.f;
          #pragma unroll
          for (int n = 0; n < 4; n++){ const float v = acc[m][n][r]; s1 += v; s2 += v*v; }
          #pragma unroll
          for (int o = 8; o; o >>= 1){ s1 += __shfl_xor(s1, o); s2 += __shfl_xor(s2, o); }
          const float mean = s1 * (1.f/64.f);
          const float inv = rsqrtf(s2 * (1.f/64.f) - mean*mean + 1e-6f);
          const long row = rowbase + wr*64 + m*16 + fq*4 + r;
          const int bq = (int)(row / 576), p = (int)(row - (long)bq*576);
          unsigned short* dst = Out + (((long)(bq*16 + h))*576 + p)*64;
          #pragma unroll
          for (int n = 0; n < 4; n++){
            const int d = n*16 + fr;
            dst[d] = f2bf(((acc[m][n][r] - mean)*inv*g[d] + bb[d]) * sc);
          }
        }
      }
    } else {
      // V third: plain f32 into Vf [4608][1024]
      #pragma unroll
      for (int m = 0; m < 4; m++){
        const long rb = rowbase + wr*64 + m*16 + fq*4;
        #pragma unroll
        for (int n = 0; n < 4; n++){
          const int vc = (cg - 2048) + n*16 + fr;
          #pragma unroll
          for (int r = 0; r < 4; r++)
            Vf[(rb + r)*1024 + vc] = acc[m][n][r];
        }
      }
    }
  } else {
    #pragma unroll
    for (int m = 0; m < 4; m++){
      const long rb = rowbase + wr * 64 + m * 16 + fq * 4;
      #pragma unroll
      for (int n = 0; n < 4; n++){
        const long cb = colbase + wc * 64 + n * 16 + fr;
        #pragma unroll
        for (int r = 0; r < 4; r++){
          const long idx = (rb + r) * N + cb;
          const float v = acc[m][n][r];
          if constexpr (EPI == 1){
            Cf[idx] = resid[idx] + (v + bias[cb]) * ls[cb];
          } else {
            Cb[idx] = f2bf(gelu_tanh(v + bias[cb]));
          }
        }
      }
    }
  }
}

// ---------------- 128x64-tile 2-phase GEMM + T1, EPI1 epilogue ----------------
// For N=1024 GEMMs (proj, MLP2): grid 16*36=576 blocks -> 2.25 blocks/CU so the
// per-K-step barrier drain overlaps across co-resident blocks (m114 mechanism).
// 4 waves as 2x2 of 64x32 wave-tiles; acc[4][2]; LDS A 8KB + B 4KB.
__global__ __launch_bounds__(256) void gemm_n64(
    const unsigned short* __restrict__ A, const unsigned short* __restrict__ Bt,
    float* __restrict__ Cf,
    const float* __restrict__ bias, const float* __restrict__ ls,
    const float* __restrict__ resid, int M, int N, int K, int gx)
{
  __shared__ __align__(16) unsigned short As[128 * 32];
  __shared__ __align__(16) unsigned short Bs[64 * 32];
  const int tid = threadIdx.x;
  const int wave = tid >> 6, lane = tid & 63;
  const int fr = lane & 15, fq = lane >> 4;
  const int wr = wave >> 1, wc = wave & 1;
  const int nwg = gridDim.x, bid = blockIdx.x;
  const int swz = ((nwg & 7) == 0) ? ((bid & 7) * (nwg >> 3) + (bid >> 3)) : bid;
  const int tx = swz % gx, ty = swz / gx;
  const long rowbase = (long)ty * 128;
  const long colbase = (long)tx * 64;

  accf4 acc[4][2];
  const accf4 zero = {0.f, 0.f, 0.f, 0.f};
  #pragma unroll
  for (int m = 0; m < 4; m++){ acc[m][0] = zero; acc[m][1] = zero; }

  const unsigned short* a0 = A + (rowbase + (tid >> 2)) * (long)K + (tid & 3) * 8;
  const unsigned short* a1 = a0 + 64l * K;
  const unsigned short* b0 = Bt + (colbase + (tid >> 2)) * (long)K + (tid & 3) * 8;
  unsigned short* lA0 = &As[wave * 512];
  unsigned short* lA1 = &As[2048 + wave * 512];
  unsigned short* lB0 = &Bs[wave * 512];

  for (int k0 = 0; k0 < K; k0 += 32){
    __syncthreads();
    gload16(a0 + k0, lA0);
    gload16(a1 + k0, lA1);
    gload16(b0 + k0, lB0);
    __syncthreads();
    frag8 af[4], bf[2];
    #pragma unroll
    for (int m = 0; m < 4; m++) af[m] = *(const frag8*)&As[(wr*64 + m*16 + fr)*32 + fq*8];
    #pragma unroll
    for (int n = 0; n < 2; n++) bf[n] = *(const frag8*)&Bs[(wc*32 + n*16 + fr)*32 + fq*8];
    #pragma unroll
    for (int m = 0; m < 4; m++)
      #pragma unroll
      for (int n = 0; n < 2; n++)
        acc[m][n] = __builtin_amdgcn_mfma_f32_16x16x32_bf16(af[m], bf[n], acc[m][n], 0, 0, 0);
  }

  #pragma unroll
  for (int m = 0; m < 4; m++){
    const long rb = rowbase + wr * 64 + m * 16 + fq * 4;
    #pragma unroll
    for (int n = 0; n < 2; n++){
      const long cb = colbase + wc * 32 + n * 16 + fr;
      #pragma unroll
      for (int r = 0; r < 4; r++){
        const long idx = (rb + r) * N + cb;
        Cf[idx] = resid[idx] + (acc[m][n][r] + bias[cb]) * ls[cb];
      }
    }
  }
}

extern "C" void kernel_launch(void* const* d_in, const int* in_sizes, int n_in,
                              void* d_out, int out_size, void* d_ws, size_t ws_size,
                              hipStream_t stream){
  (void)in_sizes; (void)n_in; (void)out_size; (void)ws_size;
  const float* x      = (const float*)d_in[0];
  const float* w_qkv  = (const float*)d_in[1];
  const float* q_g    = (const float*)d_in[2];
  const float* q_b    = (const float*)d_in[3];
  const float* k_g    = (const float*)d_in[4];
  const float* k_b    = (const float*)d_in[5];
  const float* o_g    = (const float*)d_in[6];
  const float* o_b    = (const float*)d_in[7];
  const float* w_proj = (const float*)d_in[8];
  const float* b_proj = (const float*)d_in[9];
  const float* ln1_g  = (const float*)d_in[10];
  const float* ln1_b  = (const float*)d_in[11];
  const float* ln2_g  = (const float*)d_in[12];
  const float* ln2_b  = (const float*)d_in[13];
  const float* w1     = (const float*)d_in[14];
  const float* b1     = (const float*)d_in[15];
  const float* w2     = (const float*)d_in[16];
  const float* b2     = (const float*)d_in[17];
  const float* ls1    = (const float*)d_in[18];
  const float* ls2    = (const float*)d_in[19];
  float* out = (float*)d_out;

  char* ws = (char*)d_ws;
  size_t off = 0;
  auto alloc = [&](size_t bytes)->void*{
    void* p = ws + off; off += (bytes + 255) & ~(size_t)255; return p;
  };
  unsigned short* wqkvT  = (unsigned short*)alloc(3072l*1024*2);
  unsigned short* wprojT = (unsigned short*)alloc(1024l*1024*2);
  unsigned short* w1T    = (unsigned short*)alloc(4096l*1024*2);
  unsigned short* w2T    = (unsigned short*)alloc(1024l*4096*2);
  unsigned short* xnA    = (unsigned short*)alloc(4608l*1024*2);   // xn1 / on / xn2
  float*          qkvVf  = (float*)alloc(4608l*1024*4);            // V third, f32
  unsigned short* Qn     = (unsigned short*)alloc(73728l*64*2);
  unsigned short* Kn     = (unsigned short*)alloc(73728l*64*2);
  unsigned short* Vt     = (unsigned short*)alloc(73728l*64*2);
  unsigned short* hbf    = (unsigned short*)alloc(4608l*4096*2);
  float*          attnO  = qkvVf;   // overlay: qkvVf dead after v_trans

  // weights -> bf16 B^T
  wtrans<<<dim3(3072/32, 1024/32), dim3(32,8), 0, stream>>>(w_qkv,  wqkvT,  1024, 3072);
  wtrans<<<dim3(1024/32, 1024/32), dim3(32,8), 0, stream>>>(w_proj, wprojT, 1024, 1024);
  wtrans<<<dim3(4096/32, 1024/32), dim3(32,8), 0, stream>>>(w1,     w1T,    1024, 4096);
  wtrans<<<dim3(1024/32, 4096/32), dim3(32,8), 0, stream>>>(w2,     w2T,    4096, 1024);

  // attention branch
  ln_rows<<<4608, 256, 0, stream>>>(x, ln1_g, ln1_b, xnA);
  gemm_bt<3><<<24*36, 256, 0, stream>>>(xnA, wqkvT, nullptr, nullptr,
                                        nullptr, nullptr, nullptr,
                                        q_g, q_b, k_g, k_b, Qn, Kn, qkvVf,
                                        4608, 3072, 1024, 24);
  v_trans<<<dim3(128,9), 256, 0, stream>>>(qkvVf, Vt);
  attn_k<<<dim3(36,128), 256, 0, stream>>>(Qn, Kn, Vt, attnO);
  ln_rows<<<4608, 256, 0, stream>>>(attnO, o_g, o_b, xnA);
  gemm_n64<<<16*36, 256, 0, stream>>>(xnA, wprojT, out, b_proj, ls1, x,
                                      4608, 1024, 1024, 16);
  // MLP branch
  ln_rows<<<4608, 256, 0, stream>>>(out, ln2_g, ln2_b, xnA);
  gemm_bt<2><<<32*36, 256, 0, stream>>>(xnA, w1T, nullptr, hbf,
                                        b1, nullptr, nullptr,
                                        nullptr, nullptr, nullptr, nullptr,
                                        nullptr, nullptr, nullptr,
                                        4608, 4096, 1024, 32);
  gemm_n64<<<16*36, 256, 0, stream>>>(hbf, w2T, out, b2, ls2, out,
                                      4608, 1024, 4096, 16);
}

// Round 8
// 357.432 us; speedup vs baseline: 1.0968x; 1.0015x over previous
//
#include <hip/hip_runtime.h>
#include <hip/hip_bf16.h>

#define DEV static __device__ __forceinline__

typedef short frag8 __attribute__((ext_vector_type(8)));
typedef float accf4 __attribute__((ext_vector_type(4)));

// Problem constants: B=8, P=576, D=1024, H=16, HD=64, HID=4096, BP=4608, BH=128

DEV unsigned short f2bf(float f){
  union { float f; unsigned int u; } v; v.f = f;
  unsigned int r = v.u + 0x7fffu + ((v.u >> 16) & 1u);
  return (unsigned short)(r >> 16);
}

DEV void gload16(const void* g, void* l){
  __builtin_amdgcn_global_load_lds((const __attribute__((address_space(1))) void*)g,
                                   (__attribute__((address_space(3))) void*)l, 16, 0, 0);
}

DEV float gelu_tanh(float x){
  float u = 0.7978845608028654f * (x + 0.044715f * x * x * x);
  float e = __expf(2.0f * u);
  float th = 1.0f - 2.0f / (e + 1.0f);   // tanh(u), inf-safe
  return 0.5f * x * (1.0f + th);
}

// ---------------- weight cast + transpose: W[K,N] f32 -> Wt[N,K] bf16 ----------------
__global__ __launch_bounds__(256) void wtrans(const float* __restrict__ W,
                                              unsigned short* __restrict__ Wt,
                                              int K, int N){
  __shared__ float t[32][33];
  const int n0 = blockIdx.x * 32, k0 = blockIdx.y * 32;
  const int tx = threadIdx.x, ty = threadIdx.y;   // (32,8)
  #pragma unroll
  for (int i = 0; i < 4; i++)
    t[ty + i*8][tx] = W[(long)(k0 + ty + i*8) * N + n0 + tx];
  __syncthreads();
  #pragma unroll
  for (int i = 0; i < 4; i++)
    Wt[(long)(n0 + ty + i*8) * K + k0 + tx] = f2bf(t[tx][ty + i*8]);
}

// ---------------- LayerNorm over D=1024 rows: f32 in -> bf16 out ----------------
__global__ __launch_bounds__(256) void ln_rows(const float* __restrict__ in,
                                               const float* __restrict__ g,
                                               const float* __restrict__ beta,
                                               unsigned short* __restrict__ out){
  const long row = blockIdx.x;
  const int t = threadIdx.x;
  const float4 v = ((const float4*)(in + row * 1024))[t];
  float s  = v.x + v.y + v.z + v.w;
  float s2 = v.x*v.x + v.y*v.y + v.z*v.z + v.w*v.w;
  #pragma unroll
  for (int o = 32; o; o >>= 1){ s += __shfl_xor(s, o); s2 += __shfl_xor(s2, o); }
  __shared__ float rs[4], rq[4];
  const int wv = t >> 6;
  if ((t & 63) == 0){ rs[wv] = s; rq[wv] = s2; }
  __syncthreads();
  s  = rs[0] + rs[1] + rs[2] + rs[3];
  s2 = rq[0] + rq[1] + rq[2] + rq[3];
  const float mean = s * (1.f/1024.f);
  const float inv = rsqrtf(s2 * (1.f/1024.f) - mean*mean + 1e-6f);
  const float4 gv = ((const float4*)g)[t];
  const float4 bv = ((const float4*)beta)[t];
  ushort4 o4;
  o4.x = f2bf((v.x - mean)*inv*gv.x + bv.x);
  o4.y = f2bf((v.y - mean)*inv*gv.y + bv.y);
  o4.z = f2bf((v.z - mean)*inv*gv.z + bv.z);
  o4.w = f2bf((v.w - mean)*inv*gv.w + bv.w);
  *(ushort4*)(out + row * 1024 + t * 4) = o4;
}

// ---------------- V transpose per head: qkvVf [4608][1024] f32 -> Vt [BH][64][576] bf16 ----------------
__global__ __launch_bounds__(256) void v_trans(const float* __restrict__ qkvVf,
                                               unsigned short* __restrict__ Vt){
  const int bh = blockIdx.x, pt = blockIdx.y;   // pt: 0..8 (64 p's each)
  const int b = bh >> 4, h = bh & 15;
  __shared__ float tile[64][65];
  const int t = threadIdx.x;
  #pragma unroll
  for (int i = 0; i < 16; i++){
    int idx = i * 256 + t; int p = idx >> 6, d = idx & 63;
    tile[p][d] = qkvVf[((long)(b * 576) + pt * 64 + p) * 1024 + h * 64 + d];
  }
  __syncthreads();
  #pragma unroll
  for (int i = 0; i < 16; i++){
    int idx = i * 256 + t; int d = idx >> 6, p = idx & 63;
    Vt[((long)bh * 64 + d) * 576 + pt * 64 + p] = f2bf(tile[p][d]);
  }
}

// ---------------- attention: one block = one (bh, 16-q-row tile) ----------------
__global__ __launch_bounds__(256) void attn_k(const unsigned short* __restrict__ Qn,
                                              const unsigned short* __restrict__ Kn,
                                              const unsigned short* __restrict__ Vt,
                                              float* __restrict__ O){
  const int qb = blockIdx.x;
  const int bh = blockIdx.y;
  const int b = bh >> 4, h = bh & 15;
  const int tid = threadIdx.x, wv = tid >> 6, lane = tid & 63;
  const int fr = lane & 15, fq = lane >> 4;
  __shared__ float S[16][578];
  __shared__ __align__(16) unsigned short Pl[16][584];

  const unsigned short* qbase = Qn + ((long)bh * 576 + qb * 16 + fr) * 64;
  frag8 qf0 = *(const frag8*)(qbase + fq * 8);
  frag8 qf1 = *(const frag8*)(qbase + 32 + fq * 8);

  for (int i = 0; i < 9; i++){
    const int kt = wv + 4 * i;
    const unsigned short* kbase = Kn + ((long)bh * 576 + kt * 16 + fr) * 64;
    frag8 kf0 = *(const frag8*)(kbase + fq * 8);
    frag8 kf1 = *(const frag8*)(kbase + 32 + fq * 8);
    accf4 a = {0.f, 0.f, 0.f, 0.f};
    a = __builtin_amdgcn_mfma_f32_16x16x32_bf16(qf0, kf0, a, 0, 0, 0);
    a = __builtin_amdgcn_mfma_f32_16x16x32_bf16(qf1, kf1, a, 0, 0, 0);
    #pragma unroll
    for (int rr = 0; rr < 4; rr++) S[fq * 4 + rr][kt * 16 + fr] = a[rr];
  }
  __syncthreads();

  {
    const int row = tid >> 4, cid = tid & 15;
    float vals[36];
    float mx = -1e30f;
    #pragma unroll
    for (int i = 0; i < 36; i++){ vals[i] = S[row][cid + 16 * i]; mx = fmaxf(mx, vals[i]); }
    #pragma unroll
    for (int o = 8; o; o >>= 1) mx = fmaxf(mx, __shfl_xor(mx, o));
    float sum = 0.f;
    #pragma unroll
    for (int i = 0; i < 36; i++){ vals[i] = __expf(vals[i] - mx); sum += vals[i]; }
    #pragma unroll
    for (int o = 8; o; o >>= 1) sum += __shfl_xor(sum, o);
    const float rsum = 1.f / sum;
    #pragma unroll
    for (int i = 0; i < 36; i++) Pl[row][cid + 16 * i] = f2bf(vals[i] * rsum);
  }
  __syncthreads();

  accf4 oa = {0.f, 0.f, 0.f, 0.f};
  for (int kt = 0; kt < 18; kt++){
    frag8 pf = *(const frag8*)&Pl[fr][kt * 32 + fq * 8];
    const unsigned short* vb = Vt + ((long)bh * 64 + wv * 16 + fr) * 576 + kt * 32 + fq * 8;
    frag8 vf = *(const frag8*)vb;
    oa = __builtin_amdgcn_mfma_f32_16x16x32_bf16(pf, vf, oa, 0, 0, 0);
  }
  #pragma unroll
  for (int rr = 0; rr < 4; rr++){
    const long orow = (long)b * 576 + qb * 16 + fq * 4 + rr;
    O[orow * 1024 + h * 64 + wv * 16 + fr] = oa[rr];
  }
}

// ---------------- 128x128 2-phase GEMM + T1 + LDS double-buffer ----------------
// One __syncthreads per K-step; stage(next) issued BEFORE compute(cur) so load
// latency hides under ds_read+MFMA (catalog T3 minimal recipe).
// EPI 2: Cb = bf16(gelu(acc+bias)).
// EPI 3: QKV — per-head QK-LayerNorm fused (Q scaled 0.125) -> Qn/Kn bf16; V -> Vf f32.
template<int EPI>
__global__ __launch_bounds__(256) void gemm_bt(
    const unsigned short* __restrict__ A, const unsigned short* __restrict__ Bt,
    float* __restrict__ Cf, unsigned short* __restrict__ Cb,
    const float* __restrict__ bias, const float* __restrict__ ls,
    const float* __restrict__ resid,
    const float* __restrict__ qg, const float* __restrict__ qb2,
    const float* __restrict__ kg, const float* __restrict__ kb2,
    unsigned short* __restrict__ Qn, unsigned short* __restrict__ Kn,
    float* __restrict__ Vf,
    int M, int N, int K, int gx)
{
  __shared__ __align__(16) unsigned short As[2][128 * 32];
  __shared__ __align__(16) unsigned short Bs[2][128 * 32];
  const int tid = threadIdx.x;
  const int wave = tid >> 6, lane = tid & 63;
  const int fr = lane & 15, fq = lane >> 4;
  const int wr = wave >> 1, wc = wave & 1;
  // T1: XCD-aware bijective swizzle (all launches have nwg % 8 == 0)
  const int nwg = gridDim.x, bid = blockIdx.x;
  const int swz = ((nwg & 7) == 0) ? ((bid & 7) * (nwg >> 3) + (bid >> 3)) : bid;
  const int tx = swz % gx, ty = swz / gx;
  const long rowbase = (long)ty * 128;
  const long colbase = (long)tx * 128;

  accf4 acc[4][4];
  const accf4 zero = {0.f, 0.f, 0.f, 0.f};
  #pragma unroll
  for (int m = 0; m < 4; m++)
    #pragma unroll
    for (int n = 0; n < 4; n++) acc[m][n] = zero;

  const unsigned short* a0 = A + (rowbase + (tid >> 2)) * (long)K + (tid & 3) * 8;
  const unsigned short* a1 = a0 + 64l * K;
  const unsigned short* b0 = Bt + (colbase + (tid >> 2)) * (long)K + (tid & 3) * 8;
  const unsigned short* b1 = b0 + 64l * K;

  auto stage = [&](int d, int k0){
    gload16(a0 + k0, &As[d][wave * 512]);
    gload16(a1 + k0, &As[d][2048 + wave * 512]);
    gload16(b0 + k0, &Bs[d][wave * 512]);
    gload16(b1 + k0, &Bs[d][2048 + wave * 512]);
  };
  auto compute = [&](int d){
    frag8 af[4], bf[4];
    #pragma unroll
    for (int m = 0; m < 4; m++) af[m] = *(const frag8*)&As[d][(wr*64 + m*16 + fr)*32 + fq*8];
    #pragma unroll
    for (int n = 0; n < 4; n++) bf[n] = *(const frag8*)&Bs[d][(wc*64 + n*16 + fr)*32 + fq*8];
    #pragma unroll
    for (int m = 0; m < 4; m++)
      #pragma unroll
      for (int n = 0; n < 4; n++)
        acc[m][n] = __builtin_amdgcn_mfma_f32_16x16x32_bf16(af[m], bf[n], acc[m][n], 0, 0, 0);
  };

  stage(0, 0);
  __syncthreads();
  for (int k0 = 0; k0 < K; k0 += 64){
    stage(1, k0 + 32);
    compute(0);
    __syncthreads();
    if (k0 + 64 < K) stage(0, k0 + 64);
    compute(1);
    __syncthreads();
  }

  if constexpr (EPI == 3){
    // wave owns a 64-row x 64-col tile; 64-col group = one head of one kind
    const int cg = (int)colbase + wc * 64;       // multiple of 64
    const int kind = cg >> 10;                   // 0=Q, 1=K, 2=V
    const int h = (cg & 1023) >> 6;
    if (kind < 2){
      const float* g  = kind ? kg : qg;
      const float* bb = kind ? kb2 : qb2;
      const float sc = kind ? 1.0f : 0.125f;
      unsigned short* Out = kind ? Kn : Qn;
      #pragma unroll
      for (int m = 0; m < 4; m++){
        #pragma unroll
        for (int r = 0; r < 4; r++){
          float s1 = 0.f, s2 = 0.f;
          #pragma unroll
          for (int n = 0; n < 4; n++){ const float v = acc[m][n][r]; s1 += v; s2 += v*v; }
          #pragma unroll
          for (int o = 8; o; o >>= 1){ s1 += __shfl_xor(s1, o); s2 += __shfl_xor(s2, o); }
          const float mean = s1 * (1.f/64.f);
          const float inv = rsqrtf(s2 * (1.f/64.f) - mean*mean + 1e-6f);
          const long row = rowbase + wr*64 + m*16 + fq*4 + r;
          const int bq = (int)(row / 576), p = (int)(row - (long)bq*576);
          unsigned short* dst = Out + (((long)(bq*16 + h))*576 + p)*64;
          #pragma unroll
          for (int n = 0; n < 4; n++){
            const int d = n*16 + fr;
            dst[d] = f2bf(((acc[m][n][r] - mean)*inv*g[d] + bb[d]) * sc);
          }
        }
      }
    } else {
      // V third: plain f32 into Vf [4608][1024]
      #pragma unroll
      for (int m = 0; m < 4; m++){
        const long rb = rowbase + wr*64 + m*16 + fq*4;
        #pragma unroll
        for (int n = 0; n < 4; n++){
          const int vc = (cg - 2048) + n*16 + fr;
          #pragma unroll
          for (int r = 0; r < 4; r++)
            Vf[(rb + r)*1024 + vc] = acc[m][n][r];
        }
      }
    }
  } else {
    #pragma unroll
    for (int m = 0; m < 4; m++){
      const long rb = rowbase + wr * 64 + m * 16 + fq * 4;
      #pragma unroll
      for (int n = 0; n < 4; n++){
        const long cb = colbase + wc * 64 + n * 16 + fr;
        #pragma unroll
        for (int r = 0; r < 4; r++){
          const long idx = (rb + r) * N + cb;
          const float v = acc[m][n][r];
          if constexpr (EPI == 1){
            Cf[idx] = resid[idx] + (v + bias[cb]) * ls[cb];
          } else {
            Cb[idx] = f2bf(gelu_tanh(v + bias[cb]));
          }
        }
      }
    }
  }
}

// ---------------- 128x64-tile 2-phase GEMM + T1 + LDS double-buffer, EPI1 ----------------
__global__ __launch_bounds__(256) void gemm_n64(
    const unsigned short* __restrict__ A, const unsigned short* __restrict__ Bt,
    float* __restrict__ Cf,
    const float* __restrict__ bias, const float* __restrict__ ls,
    const float* __restrict__ resid, int M, int N, int K, int gx)
{
  __shared__ __align__(16) unsigned short As[2][128 * 32];
  __shared__ __align__(16) unsigned short Bs[2][64 * 32];
  const int tid = threadIdx.x;
  const int wave = tid >> 6, lane = tid & 63;
  const int fr = lane & 15, fq = lane >> 4;
  const int wr = wave >> 1, wc = wave & 1;
  const int nwg = gridDim.x, bid = blockIdx.x;
  const int swz = ((nwg & 7) == 0) ? ((bid & 7) * (nwg >> 3) + (bid >> 3)) : bid;
  const int tx = swz % gx, ty = swz / gx;
  const long rowbase = (long)ty * 128;
  const long colbase = (long)tx * 64;

  accf4 acc[4][2];
  const accf4 zero = {0.f, 0.f, 0.f, 0.f};
  #pragma unroll
  for (int m = 0; m < 4; m++){ acc[m][0] = zero; acc[m][1] = zero; }

  const unsigned short* a0 = A + (rowbase + (tid >> 2)) * (long)K + (tid & 3) * 8;
  const unsigned short* a1 = a0 + 64l * K;
  const unsigned short* b0 = Bt + (colbase + (tid >> 2)) * (long)K + (tid & 3) * 8;

  auto stage = [&](int d, int k0){
    gload16(a0 + k0, &As[d][wave * 512]);
    gload16(a1 + k0, &As[d][2048 + wave * 512]);
    gload16(b0 + k0, &Bs[d][wave * 512]);
  };
  auto compute = [&](int d){
    frag8 af[4], bf[2];
    #pragma unroll
    for (int m = 0; m < 4; m++) af[m] = *(const frag8*)&As[d][(wr*64 + m*16 + fr)*32 + fq*8];
    #pragma unroll
    for (int n = 0; n < 2; n++) bf[n] = *(const frag8*)&Bs[d][(wc*32 + n*16 + fr)*32 + fq*8];
    #pragma unroll
    for (int m = 0; m < 4; m++)
      #pragma unroll
      for (int n = 0; n < 2; n++)
        acc[m][n] = __builtin_amdgcn_mfma_f32_16x16x32_bf16(af[m], bf[n], acc[m][n], 0, 0, 0);
  };

  stage(0, 0);
  __syncthreads();
  for (int k0 = 0; k0 < K; k0 += 64){
    stage(1, k0 + 32);
    compute(0);
    __syncthreads();
    if (k0 + 64 < K) stage(0, k0 + 64);
    compute(1);
    __syncthreads();
  }

  #pragma unroll
  for (int m = 0; m < 4; m++){
    const long rb = rowbase + wr * 64 + m * 16 + fq * 4;
    #pragma unroll
    for (int n = 0; n < 2; n++){
      const long cb = colbase + wc * 32 + n * 16 + fr;
      #pragma unroll
      for (int r = 0; r < 4; r++){
        const long idx = (rb + r) * N + cb;
        Cf[idx] = resid[idx] + (acc[m][n][r] + bias[cb]) * ls[cb];
      }
    }
  }
}

extern "C" void kernel_launch(void* const* d_in, const int* in_sizes, int n_in,
                              void* d_out, int out_size, void* d_ws, size_t ws_size,
                              hipStream_t stream){
  (void)in_sizes; (void)n_in; (void)out_size; (void)ws_size;
  const float* x      = (const float*)d_in[0];
  const float* w_qkv  = (const float*)d_in[1];
  const float* q_g    = (const float*)d_in[2];
  const float* q_b    = (const float*)d_in[3];
  const float* k_g    = (const float*)d_in[4];
  const float* k_b    = (const float*)d_in[5];
  const float* o_g    = (const float*)d_in[6];
  const float* o_b    = (const float*)d_in[7];
  const float* w_proj = (const float*)d_in[8];
  const float* b_proj = (const float*)d_in[9];
  const float* ln1_g  = (const float*)d_in[10];
  const float* ln1_b  = (const float*)d_in[11];
  const float* ln2_g  = (const float*)d_in[12];
  const float* ln2_b  = (const float*)d_in[13];
  const float* w1     = (const float*)d_in[14];
  const float* b1     = (const float*)d_in[15];
  const float* w2     = (const float*)d_in[16];
  const float* b2     = (const float*)d_in[17];
  const float* ls1    = (const float*)d_in[18];
  const float* ls2    = (const float*)d_in[19];
  float* out = (float*)d_out;

  char* ws = (char*)d_ws;
  size_t off = 0;
  auto alloc = [&](size_t bytes)->void*{
    void* p = ws + off; off += (bytes + 255) & ~(size_t)255; return p;
  };
  unsigned short* wqkvT  = (unsigned short*)alloc(3072l*1024*2);
  unsigned short* wprojT = (unsigned short*)alloc(1024l*1024*2);
  unsigned short* w1T    = (unsigned short*)alloc(4096l*1024*2);
  unsigned short* w2T    = (unsigned short*)alloc(1024l*4096*2);
  unsigned short* xnA    = (unsigned short*)alloc(4608l*1024*2);   // xn1 / on / xn2
  float*          qkvVf  = (float*)alloc(4608l*1024*4);            // V third, f32
  unsigned short* Qn     = (unsigned short*)alloc(73728l*64*2);
  unsigned short* Kn     = (unsigned short*)alloc(73728l*64*2);
  unsigned short* Vt     = (unsigned short*)alloc(73728l*64*2);
  unsigned short* hbf    = (unsigned short*)alloc(4608l*4096*2);
  float*          attnO  = qkvVf;   // overlay: qkvVf dead after v_trans

  // weights -> bf16 B^T
  wtrans<<<dim3(3072/32, 1024/32), dim3(32,8), 0, stream>>>(w_qkv,  wqkvT,  1024, 3072);
  wtrans<<<dim3(1024/32, 1024/32), dim3(32,8), 0, stream>>>(w_proj, wprojT, 1024, 1024);
  wtrans<<<dim3(4096/32, 1024/32), dim3(32,8), 0, stream>>>(w1,     w1T,    1024, 4096);
  wtrans<<<dim3(1024/32, 4096/32), dim3(32,8), 0, stream>>>(w2,     w2T,    4096, 1024);

  // attention branch
  ln_rows<<<4608, 256, 0, stream>>>(x, ln1_g, ln1_b, xnA);
  gemm_bt<3><<<24*36, 256, 0, stream>>>(xnA, wqkvT, nullptr, nullptr,
                                        nullptr, nullptr, nullptr,
                                        q_g, q_b, k_g, k_b, Qn, Kn, qkvVf,
                                        4608, 3072, 1024, 24);
  v_trans<<<dim3(128,9), 256, 0, stream>>>(qkvVf, Vt);
  attn_k<<<dim3(36,128), 256, 0, stream>>>(Qn, Kn, Vt, attnO);
  ln_rows<<<4608, 256, 0, stream>>>(attnO, o_g, o_b, xnA);
  gemm_n64<<<16*36, 256, 0, stream>>>(xnA, wprojT, out, b_proj, ls1, x,
                                      4608, 1024, 1024, 16);
  // MLP branch
  ln_rows<<<4608, 256, 0, stream>>>(out, ln2_g, ln2_b, xnA);
  gemm_bt<2><<<32*36, 256, 0, stream>>>(xnA, w1T, nullptr, hbf,
                                        b1, nullptr, nullptr,
                                        nullptr, nullptr, nullptr, nullptr,
                                        nullptr, nullptr, nullptr,
                                        4608, 4096, 1024, 32);
  gemm_n64<<<16*36, 256, 0, stream>>>(hbf, w2T, out, b2, ls2, out,
                                      4608, 1024, 4096, 16);
}

// Round 9
// 341.119 us; speedup vs baseline: 1.1493x; 1.0478x over previous
//
#include <hip/hip_runtime.h>
#include <hip/hip_bf16.h>

#define DEV static __device__ __forceinline__

typedef short frag8 __attribute__((ext_vector_type(8)));
typedef float accf4 __attribute__((ext_vector_type(4)));

// Problem constants: B=8, P=576, D=1024, H=16, HD=64, HID=4096, BP=4608, BH=128

DEV unsigned short f2bf(float f){
  union { float f; unsigned int u; } v; v.f = f;
  unsigned int r = v.u + 0x7fffu + ((v.u >> 16) & 1u);
  return (unsigned short)(r >> 16);
}

DEV void gload16(const void* g, void* l){
  __builtin_amdgcn_global_load_lds((const __attribute__((address_space(1))) void*)g,
                                   (__attribute__((address_space(3))) void*)l, 16, 0, 0);
}

DEV float gelu_tanh(float x){
  float u = 0.7978845608028654f * (x + 0.044715f * x * x * x);
  float e = __expf(2.0f * u);
  float th = 1.0f - 2.0f / (e + 1.0f);   // tanh(u), inf-safe
  return 0.5f * x * (1.0f + th);
}

// T1 XCD chunking + GW=16 column-grouped within-chunk mapping.
DEV void block_map(int bid, int nwg, int gx, int& tx, int& ty){
  const int swz = ((nwg & 7) == 0) ? ((bid & 7) * (nwg >> 3) + (bid >> 3)) : bid;
  const int gy = nwg / gx;
  const int cg = swz / (gy * 16);
  const int rr = swz - cg * gy * 16;
  const int gw = min(16, gx - cg * 16);
  tx = cg * 16 + rr % gw;
  ty = rr / gw;
}

// ---------------- weight cast + transpose: W[K,N] f32 -> Wt[N,K] bf16 ----------------
__global__ __launch_bounds__(256) void wtrans(const float* __restrict__ W,
                                              unsigned short* __restrict__ Wt,
                                              int K, int N){
  __shared__ float t[32][33];
  const int n0 = blockIdx.x * 32, k0 = blockIdx.y * 32;
  const int tx = threadIdx.x, ty = threadIdx.y;   // (32,8)
  #pragma unroll
  for (int i = 0; i < 4; i++)
    t[ty + i*8][tx] = W[(long)(k0 + ty + i*8) * N + n0 + tx];
  __syncthreads();
  #pragma unroll
  for (int i = 0; i < 4; i++)
    Wt[(long)(n0 + ty + i*8) * K + k0 + tx] = f2bf(t[tx][ty + i*8]);
}

// ---------------- LayerNorm over D=1024 rows: f32 in -> bf16 out ----------------
__global__ __launch_bounds__(256) void ln_rows(const float* __restrict__ in,
                                               const float* __restrict__ g,
                                               const float* __restrict__ beta,
                                               unsigned short* __restrict__ out){
  const long row = blockIdx.x;
  const int t = threadIdx.x;
  const float4 v = ((const float4*)(in + row * 1024))[t];
  float s  = v.x + v.y + v.z + v.w;
  float s2 = v.x*v.x + v.y*v.y + v.z*v.z + v.w*v.w;
  #pragma unroll
  for (int o = 32; o; o >>= 1){ s += __shfl_xor(s, o); s2 += __shfl_xor(s2, o); }
  __shared__ float rs[4], rq[4];
  const int wv = t >> 6;
  if ((t & 63) == 0){ rs[wv] = s; rq[wv] = s2; }
  __syncthreads();
  s  = rs[0] + rs[1] + rs[2] + rs[3];
  s2 = rq[0] + rq[1] + rq[2] + rq[3];
  const float mean = s * (1.f/1024.f);
  const float inv = rsqrtf(s2 * (1.f/1024.f) - mean*mean + 1e-6f);
  const float4 gv = ((const float4*)g)[t];
  const float4 bv = ((const float4*)beta)[t];
  ushort4 o4;
  o4.x = f2bf((v.x - mean)*inv*gv.x + bv.x);
  o4.y = f2bf((v.y - mean)*inv*gv.y + bv.y);
  o4.z = f2bf((v.z - mean)*inv*gv.z + bv.z);
  o4.w = f2bf((v.w - mean)*inv*gv.w + bv.w);
  *(ushort4*)(out + row * 1024 + t * 4) = o4;
}

// ---------------- V transpose per head: qkvVf [4608][1024] f32 -> Vt [BH][64][576] bf16 ----------------
__global__ __launch_bounds__(256) void v_trans(const float* __restrict__ qkvVf,
                                               unsigned short* __restrict__ Vt){
  const int bh = blockIdx.x, pt = blockIdx.y;   // pt: 0..8 (64 p's each)
  const int b = bh >> 4, h = bh & 15;
  __shared__ float tile[64][65];
  const int t = threadIdx.x;
  #pragma unroll
  for (int i = 0; i < 16; i++){
    int idx = i * 256 + t; int p = idx >> 6, d = idx & 63;
    tile[p][d] = qkvVf[((long)(b * 576) + pt * 64 + p) * 1024 + h * 64 + d];
  }
  __syncthreads();
  #pragma unroll
  for (int i = 0; i < 16; i++){
    int idx = i * 256 + t; int d = idx >> 6, p = idx & 63;
    Vt[((long)bh * 64 + d) * 576 + pt * 64 + p] = f2bf(tile[p][d]);
  }
}

// ---------------- attention: one block = one (bh, 16-q-row tile) ----------------
__global__ __launch_bounds__(256) void attn_k(const unsigned short* __restrict__ Qn,
                                              const unsigned short* __restrict__ Kn,
                                              const unsigned short* __restrict__ Vt,
                                              float* __restrict__ O){
  const int qb = blockIdx.x;
  const int bh = blockIdx.y;
  const int b = bh >> 4, h = bh & 15;
  const int tid = threadIdx.x, wv = tid >> 6, lane = tid & 63;
  const int fr = lane & 15, fq = lane >> 4;
  __shared__ float S[16][578];
  __shared__ __align__(16) unsigned short Pl[16][584];

  const unsigned short* qbase = Qn + ((long)bh * 576 + qb * 16 + fr) * 64;
  frag8 qf0 = *(const frag8*)(qbase + fq * 8);
  frag8 qf1 = *(const frag8*)(qbase + 32 + fq * 8);

  for (int i = 0; i < 9; i++){
    const int kt = wv + 4 * i;
    const unsigned short* kbase = Kn + ((long)bh * 576 + kt * 16 + fr) * 64;
    frag8 kf0 = *(const frag8*)(kbase + fq * 8);
    frag8 kf1 = *(const frag8*)(kbase + 32 + fq * 8);
    accf4 a = {0.f, 0.f, 0.f, 0.f};
    a = __builtin_amdgcn_mfma_f32_16x16x32_bf16(qf0, kf0, a, 0, 0, 0);
    a = __builtin_amdgcn_mfma_f32_16x16x32_bf16(qf1, kf1, a, 0, 0, 0);
    #pragma unroll
    for (int rr = 0; rr < 4; rr++) S[fq * 4 + rr][kt * 16 + fr] = a[rr];
  }
  __syncthreads();

  {
    const int row = tid >> 4, cid = tid & 15;
    float vals[36];
    float mx = -1e30f;
    #pragma unroll
    for (int i = 0; i < 36; i++){ vals[i] = S[row][cid + 16 * i]; mx = fmaxf(mx, vals[i]); }
    #pragma unroll
    for (int o = 8; o; o >>= 1) mx = fmaxf(mx, __shfl_xor(mx, o));
    float sum = 0.f;
    #pragma unroll
    for (int i = 0; i < 36; i++){ vals[i] = __expf(vals[i] - mx); sum += vals[i]; }
    #pragma unroll
    for (int o = 8; o; o >>= 1) sum += __shfl_xor(sum, o);
    const float rsum = 1.f / sum;
    #pragma unroll
    for (int i = 0; i < 36; i++) Pl[row][cid + 16 * i] = f2bf(vals[i] * rsum);
  }
  __syncthreads();

  accf4 oa = {0.f, 0.f, 0.f, 0.f};
  for (int kt = 0; kt < 18; kt++){
    frag8 pf = *(const frag8*)&Pl[fr][kt * 32 + fq * 8];
    const unsigned short* vb = Vt + ((long)bh * 64 + wv * 16 + fr) * 576 + kt * 32 + fq * 8;
    frag8 vf = *(const frag8*)vb;
    oa = __builtin_amdgcn_mfma_f32_16x16x32_bf16(pf, vf, oa, 0, 0, 0);
  }
  #pragma unroll
  for (int rr = 0; rr < 4; rr++){
    const long orow = (long)b * 576 + qb * 16 + fq * 4 + rr;
    O[orow * 1024 + h * 64 + wv * 16 + fr] = oa[rr];
  }
}

// ---------------- 128x128 GEMM, depth-2 counted-vmcnt pipeline (T4), T1+GW16 ----------------
// 3 LDS buffers; stage(t+2) issued after barrier; s_waitcnt vmcnt(4) waits only the
// oldest stage (4 gload16/wave/stage). Tail drains with vmcnt(0).
// EPI 2: Cb = bf16(gelu(acc+bias)).
// EPI 3: QKV — fused per-head QK-LayerNorm (Q scaled 0.125) -> Qn/Kn bf16; V -> Vf f32.
template<int EPI>
__global__ __launch_bounds__(256) void gemm_bt(
    const unsigned short* __restrict__ A, const unsigned short* __restrict__ Bt,
    float* __restrict__ Cf, unsigned short* __restrict__ Cb,
    const float* __restrict__ bias, const float* __restrict__ ls,
    const float* __restrict__ resid,
    const float* __restrict__ qg, const float* __restrict__ qb2,
    const float* __restrict__ kg, const float* __restrict__ kb2,
    unsigned short* __restrict__ Qn, unsigned short* __restrict__ Kn,
    float* __restrict__ Vf,
    int M, int N, int K, int gx)
{
  __shared__ __align__(16) unsigned short As[3][128 * 32];
  __shared__ __align__(16) unsigned short Bs[3][128 * 32];
  const int tid = threadIdx.x;
  const int wave = tid >> 6, lane = tid & 63;
  const int fr = lane & 15, fq = lane >> 4;
  const int wr = wave >> 1, wc = wave & 1;
  int tx, ty;
  block_map(blockIdx.x, gridDim.x, gx, tx, ty);
  const long rowbase = (long)ty * 128;
  const long colbase = (long)tx * 128;

  accf4 acc[4][4];
  const accf4 zero = {0.f, 0.f, 0.f, 0.f};
  #pragma unroll
  for (int m = 0; m < 4; m++)
    #pragma unroll
    for (int n = 0; n < 4; n++) acc[m][n] = zero;

  const unsigned short* a0 = A + (rowbase + (tid >> 2)) * (long)K + (tid & 3) * 8;
  const unsigned short* a1 = a0 + 64l * K;
  const unsigned short* b0 = Bt + (colbase + (tid >> 2)) * (long)K + (tid & 3) * 8;
  const unsigned short* b1 = b0 + 64l * K;

  auto stage = [&](int d, int t){
    const int k0 = t << 5;
    gload16(a0 + k0, &As[d][wave * 512]);
    gload16(a1 + k0, &As[d][2048 + wave * 512]);
    gload16(b0 + k0, &Bs[d][wave * 512]);
    gload16(b1 + k0, &Bs[d][2048 + wave * 512]);
  };
  auto compute = [&](int d){
    frag8 af[4], bf[4];
    #pragma unroll
    for (int m = 0; m < 4; m++) af[m] = *(const frag8*)&As[d][(wr*64 + m*16 + fr)*32 + fq*8];
    #pragma unroll
    for (int n = 0; n < 4; n++) bf[n] = *(const frag8*)&Bs[d][(wc*64 + n*16 + fr)*32 + fq*8];
    #pragma unroll
    for (int m = 0; m < 4; m++)
      #pragma unroll
      for (int n = 0; n < 4; n++)
        acc[m][n] = __builtin_amdgcn_mfma_f32_16x16x32_bf16(af[m], bf[n], acc[m][n], 0, 0, 0);
  };

  const int NT = K >> 5;
  stage(0, 0);
  stage(1, 1);
  int cur = 0;
  for (int t = 0; t < NT; ++t){
    if (t + 2 < NT) asm volatile("s_waitcnt vmcnt(4)" ::: "memory");
    else            asm volatile("s_waitcnt vmcnt(0)" ::: "memory");
    __builtin_amdgcn_s_barrier();
    __builtin_amdgcn_sched_barrier(0);
    if (t + 2 < NT){
      int nb = cur + 2; if (nb >= 3) nb -= 3;
      stage(nb, t + 2);
    }
    compute(cur);
    cur = cur + 1; if (cur == 3) cur = 0;
    __builtin_amdgcn_s_barrier();
    __builtin_amdgcn_sched_barrier(0);
  }

  if constexpr (EPI == 3){
    // wave owns a 64-row x 64-col tile; 64-col group = one head of one kind
    const int cg = (int)colbase + wc * 64;       // multiple of 64
    const int kind = cg >> 10;                   // 0=Q, 1=K, 2=V
    const int h = (cg & 1023) >> 6;
    if (kind < 2){
      const float* g  = kind ? kg : qg;
      const float* bb = kind ? kb2 : qb2;
      const float sc = kind ? 1.0f : 0.125f;
      unsigned short* Out = kind ? Kn : Qn;
      #pragma unroll
      for (int m = 0; m < 4; m++){
        #pragma unroll
        for (int r = 0; r < 4; r++){
          float s1 = 0.f, s2 = 0.f;
          #pragma unroll
          for (int n = 0; n < 4; n++){ const float v = acc[m][n][r]; s1 += v; s2 += v*v; }
          #pragma unroll
          for (int o = 8; o; o >>= 1){ s1 += __shfl_xor(s1, o); s2 += __shfl_xor(s2, o); }
          const float mean = s1 * (1.f/64.f);
          const float inv = rsqrtf(s2 * (1.f/64.f) - mean*mean + 1e-6f);
          const long row = rowbase + wr*64 + m*16 + fq*4 + r;
          const int bq = (int)(row / 576), p = (int)(row - (long)bq*576);
          unsigned short* dst = Out + (((long)(bq*16 + h))*576 + p)*64;
          #pragma unroll
          for (int n = 0; n < 4; n++){
            const int d = n*16 + fr;
            dst[d] = f2bf(((acc[m][n][r] - mean)*inv*g[d] + bb[d]) * sc);
          }
        }
      }
    } else {
      // V third: plain f32 into Vf [4608][1024]
      #pragma unroll
      for (int m = 0; m < 4; m++){
        const long rb = rowbase + wr*64 + m*16 + fq*4;
        #pragma unroll
        for (int n = 0; n < 4; n++){
          const int vc = (cg - 2048) + n*16 + fr;
          #pragma unroll
          for (int r = 0; r < 4; r++)
            Vf[(rb + r)*1024 + vc] = acc[m][n][r];
        }
      }
    }
  } else {
    #pragma unroll
    for (int m = 0; m < 4; m++){
      const long rb = rowbase + wr * 64 + m * 16 + fq * 4;
      #pragma unroll
      for (int n = 0; n < 4; n++){
        const long cb = colbase + wc * 64 + n * 16 + fr;
        #pragma unroll
        for (int r = 0; r < 4; r++){
          const long idx = (rb + r) * N + cb;
          const float v = acc[m][n][r];
          if constexpr (EPI == 1){
            Cf[idx] = resid[idx] + (v + bias[cb]) * ls[cb];
          } else {
            Cb[idx] = f2bf(gelu_tanh(v + bias[cb]));
          }
        }
      }
    }
  }
}

// ---------------- 128x64 GEMM, depth-2 counted-vmcnt pipeline, EPI1 ----------------
__global__ __launch_bounds__(256) void gemm_n64(
    const unsigned short* __restrict__ A, const unsigned short* __restrict__ Bt,
    float* __restrict__ Cf,
    const float* __restrict__ bias, const float* __restrict__ ls,
    const float* __restrict__ resid, int M, int N, int K, int gx)
{
  __shared__ __align__(16) unsigned short As[3][128 * 32];
  __shared__ __align__(16) unsigned short Bs[3][64 * 32];
  const int tid = threadIdx.x;
  const int wave = tid >> 6, lane = tid & 63;
  const int fr = lane & 15, fq = lane >> 4;
  const int wr = wave >> 1, wc = wave & 1;
  int tx, ty;
  block_map(blockIdx.x, gridDim.x, gx, tx, ty);
  const long rowbase = (long)ty * 128;
  const long colbase = (long)tx * 64;

  accf4 acc[4][2];
  const accf4 zero = {0.f, 0.f, 0.f, 0.f};
  #pragma unroll
  for (int m = 0; m < 4; m++){ acc[m][0] = zero; acc[m][1] = zero; }

  const unsigned short* a0 = A + (rowbase + (tid >> 2)) * (long)K + (tid & 3) * 8;
  const unsigned short* a1 = a0 + 64l * K;
  const unsigned short* b0 = Bt + (colbase + (tid >> 2)) * (long)K + (tid & 3) * 8;

  auto stage = [&](int d, int t){
    const int k0 = t << 5;
    gload16(a0 + k0, &As[d][wave * 512]);
    gload16(a1 + k0, &As[d][2048 + wave * 512]);
    gload16(b0 + k0, &Bs[d][wave * 512]);
  };
  auto compute = [&](int d){
    frag8 af[4], bf[2];
    #pragma unroll
    for (int m = 0; m < 4; m++) af[m] = *(const frag8*)&As[d][(wr*64 + m*16 + fr)*32 + fq*8];
    #pragma unroll
    for (int n = 0; n < 2; n++) bf[n] = *(const frag8*)&Bs[d][(wc*32 + n*16 + fr)*32 + fq*8];
    #pragma unroll
    for (int m = 0; m < 4; m++)
      #pragma unroll
      for (int n = 0; n < 2; n++)
        acc[m][n] = __builtin_amdgcn_mfma_f32_16x16x32_bf16(af[m], bf[n], acc[m][n], 0, 0, 0);
  };

  const int NT = K >> 5;
  stage(0, 0);
  stage(1, 1);
  int cur = 0;
  for (int t = 0; t < NT; ++t){
    if (t + 2 < NT) asm volatile("s_waitcnt vmcnt(3)" ::: "memory");
    else            asm volatile("s_waitcnt vmcnt(0)" ::: "memory");
    __builtin_amdgcn_s_barrier();
    __builtin_amdgcn_sched_barrier(0);
    if (t + 2 < NT){
      int nb = cur + 2; if (nb >= 3) nb -= 3;
      stage(nb, t + 2);
    }
    compute(cur);
    cur = cur + 1; if (cur == 3) cur = 0;
    __builtin_amdgcn_s_barrier();
    __builtin_amdgcn_sched_barrier(0);
  }

  #pragma unroll
  for (int m = 0; m < 4; m++){
    const long rb = rowbase + wr * 64 + m * 16 + fq * 4;
    #pragma unroll
    for (int n = 0; n < 2; n++){
      const long cb = colbase + wc * 32 + n * 16 + fr;
      #pragma unroll
      for (int r = 0; r < 4; r++){
        const long idx = (rb + r) * N + cb;
        Cf[idx] = resid[idx] + (acc[m][n][r] + bias[cb]) * ls[cb];
      }
    }
  }
}

extern "C" void kernel_launch(void* const* d_in, const int* in_sizes, int n_in,
                              void* d_out, int out_size, void* d_ws, size_t ws_size,
                              hipStream_t stream){
  (void)in_sizes; (void)n_in; (void)out_size; (void)ws_size;
  const float* x      = (const float*)d_in[0];
  const float* w_qkv  = (const float*)d_in[1];
  const float* q_g    = (const float*)d_in[2];
  const float* q_b    = (const float*)d_in[3];
  const float* k_g    = (const float*)d_in[4];
  const float* k_b    = (const float*)d_in[5];
  const float* o_g    = (const float*)d_in[6];
  const float* o_b    = (const float*)d_in[7];
  const float* w_proj = (const float*)d_in[8];
  const float* b_proj = (const float*)d_in[9];
  const float* ln1_g  = (const float*)d_in[10];
  const float* ln1_b  = (const float*)d_in[11];
  const float* ln2_g  = (const float*)d_in[12];
  const float* ln2_b  = (const float*)d_in[13];
  const float* w1     = (const float*)d_in[14];
  const float* b1     = (const float*)d_in[15];
  const float* w2     = (const float*)d_in[16];
  const float* b2     = (const float*)d_in[17];
  const float* ls1    = (const float*)d_in[18];
  const float* ls2    = (const float*)d_in[19];
  float* out = (float*)d_out;

  char* ws = (char*)d_ws;
  size_t off = 0;
  auto alloc = [&](size_t bytes)->void*{
    void* p = ws + off; off += (bytes + 255) & ~(size_t)255; return p;
  };
  unsigned short* wqkvT  = (unsigned short*)alloc(3072l*1024*2);
  unsigned short* wprojT = (unsigned short*)alloc(1024l*1024*2);
  unsigned short* w1T    = (unsigned short*)alloc(4096l*1024*2);
  unsigned short* w2T    = (unsigned short*)alloc(1024l*4096*2);
  unsigned short* xnA    = (unsigned short*)alloc(4608l*1024*2);   // xn1 / on / xn2
  float*          qkvVf  = (float*)alloc(4608l*1024*4);            // V third, f32
  unsigned short* Qn     = (unsigned short*)alloc(73728l*64*2);
  unsigned short* Kn     = (unsigned short*)alloc(73728l*64*2);
  unsigned short* Vt     = (unsigned short*)alloc(73728l*64*2);
  unsigned short* hbf    = (unsigned short*)alloc(4608l*4096*2);
  float*          attnO  = qkvVf;   // overlay: qkvVf dead after v_trans

  // weights -> bf16 B^T
  wtrans<<<dim3(3072/32, 1024/32), dim3(32,8), 0, stream>>>(w_qkv,  wqkvT,  1024, 3072);
  wtrans<<<dim3(1024/32, 1024/32), dim3(32,8), 0, stream>>>(w_proj, wprojT, 1024, 1024);
  wtrans<<<dim3(4096/32, 1024/32), dim3(32,8), 0, stream>>>(w1,     w1T,    1024, 4096);
  wtrans<<<dim3(1024/32, 4096/32), dim3(32,8), 0, stream>>>(w2,     w2T,    4096, 1024);

  // attention branch
  ln_rows<<<4608, 256, 0, stream>>>(x, ln1_g, ln1_b, xnA);
  gemm_bt<3><<<24*36, 256, 0, stream>>>(xnA, wqkvT, nullptr, nullptr,
                                        nullptr, nullptr, nullptr,
                                        q_g, q_b, k_g, k_b, Qn, Kn, qkvVf,
                                        4608, 3072, 1024, 24);
  v_trans<<<dim3(128,9), 256, 0, stream>>>(qkvVf, Vt);
  attn_k<<<dim3(36,128), 256, 0, stream>>>(Qn, Kn, Vt, attnO);
  ln_rows<<<4608, 256, 0, stream>>>(attnO, o_g, o_b, xnA);
  gemm_n64<<<16*36, 256, 0, stream>>>(xnA, wprojT, out, b_proj, ls1, x,
                                      4608, 1024, 1024, 16);
  // MLP branch
  ln_rows<<<4608, 256, 0, stream>>>(out, ln2_g, ln2_b, xnA);
  gemm_bt<2><<<32*36, 256, 0, stream>>>(xnA, w1T, nullptr, hbf,
                                        b1, nullptr, nullptr,
                                        nullptr, nullptr, nullptr, nullptr,
                                        nullptr, nullptr, nullptr,
                                        4608, 4096, 1024, 32);
  gemm_n64<<<16*36, 256, 0, stream>>>(hbf, w2T, out, b2, ls2, out,
                                      4608, 1024, 4096, 16);
}

// Round 10
// 338.570 us; speedup vs baseline: 1.1579x; 1.0075x over previous
//
#include <hip/hip_runtime.h>
#include <hip/hip_bf16.h>

#define DEV static __device__ __forceinline__

typedef short frag8 __attribute__((ext_vector_type(8)));
typedef float accf4 __attribute__((ext_vector_type(4)));

// Problem constants: B=8, P=576, D=1024, H=16, HD=64, HID=4096, BP=4608, BH=128

DEV unsigned short f2bf(float f){
  union { float f; unsigned int u; } v; v.f = f;
  unsigned int r = v.u + 0x7fffu + ((v.u >> 16) & 1u);
  return (unsigned short)(r >> 16);
}

DEV void gload16(const void* g, void* l){
  __builtin_amdgcn_global_load_lds((const __attribute__((address_space(1))) void*)g,
                                   (__attribute__((address_space(3))) void*)l, 16, 0, 0);
}

DEV float gelu_tanh(float x){
  float u = 0.7978845608028654f * (x + 0.044715f * x * x * x);
  float e = __expf(2.0f * u);
  float th = 1.0f - 2.0f / (e + 1.0f);   // tanh(u), inf-safe
  return 0.5f * x * (1.0f + th);
}

// T1 XCD chunking + GW=16 column-grouped within-chunk mapping.
DEV void block_map(int bid, int nwg, int gx, int& tx, int& ty){
  const int swz = ((nwg & 7) == 0) ? ((bid & 7) * (nwg >> 3) + (bid >> 3)) : bid;
  const int gy = nwg / gx;
  const int cg = swz / (gy * 16);
  const int rr = swz - cg * gy * 16;
  const int gw = min(16, gx - cg * 16);
  tx = cg * 16 + rr % gw;
  ty = rr / gw;
}

// ---------------- weight cast + transpose: W[K,N] f32 -> Wt[N,K] bf16 ----------------
__global__ __launch_bounds__(256) void wtrans(const float* __restrict__ W,
                                              unsigned short* __restrict__ Wt,
                                              int K, int N){
  __shared__ float t[32][33];
  const int n0 = blockIdx.x * 32, k0 = blockIdx.y * 32;
  const int tx = threadIdx.x, ty = threadIdx.y;   // (32,8)
  #pragma unroll
  for (int i = 0; i < 4; i++)
    t[ty + i*8][tx] = W[(long)(k0 + ty + i*8) * N + n0 + tx];
  __syncthreads();
  #pragma unroll
  for (int i = 0; i < 4; i++)
    Wt[(long)(n0 + ty + i*8) * K + k0 + tx] = f2bf(t[tx][ty + i*8]);
}

// ---------------- LayerNorm over D=1024 rows: f32 in -> bf16 out ----------------
__global__ __launch_bounds__(256) void ln_rows(const float* __restrict__ in,
                                               const float* __restrict__ g,
                                               const float* __restrict__ beta,
                                               unsigned short* __restrict__ out){
  const long row = blockIdx.x;
  const int t = threadIdx.x;
  const float4 v = ((const float4*)(in + row * 1024))[t];
  float s  = v.x + v.y + v.z + v.w;
  float s2 = v.x*v.x + v.y*v.y + v.z*v.z + v.w*v.w;
  #pragma unroll
  for (int o = 32; o; o >>= 1){ s += __shfl_xor(s, o); s2 += __shfl_xor(s2, o); }
  __shared__ float rs[4], rq[4];
  const int wv = t >> 6;
  if ((t & 63) == 0){ rs[wv] = s; rq[wv] = s2; }
  __syncthreads();
  s  = rs[0] + rs[1] + rs[2] + rs[3];
  s2 = rq[0] + rq[1] + rq[2] + rq[3];
  const float mean = s * (1.f/1024.f);
  const float inv = rsqrtf(s2 * (1.f/1024.f) - mean*mean + 1e-6f);
  const float4 gv = ((const float4*)g)[t];
  const float4 bv = ((const float4*)beta)[t];
  ushort4 o4;
  o4.x = f2bf((v.x - mean)*inv*gv.x + bv.x);
  o4.y = f2bf((v.y - mean)*inv*gv.y + bv.y);
  o4.z = f2bf((v.z - mean)*inv*gv.z + bv.z);
  o4.w = f2bf((v.w - mean)*inv*gv.w + bv.w);
  *(ushort4*)(out + row * 1024 + t * 4) = o4;
}

// ---------------- V transpose per head: qkvVf [4608][1024] f32 -> Vt [BH][64][576] bf16 ----------------
__global__ __launch_bounds__(256) void v_trans(const float* __restrict__ qkvVf,
                                               unsigned short* __restrict__ Vt){
  const int bh = blockIdx.x, pt = blockIdx.y;   // pt: 0..8 (64 p's each)
  const int b = bh >> 4, h = bh & 15;
  __shared__ float tile[64][65];
  const int t = threadIdx.x;
  #pragma unroll
  for (int i = 0; i < 16; i++){
    int idx = i * 256 + t; int p = idx >> 6, d = idx & 63;
    tile[p][d] = qkvVf[((long)(b * 576) + pt * 64 + p) * 1024 + h * 64 + d];
  }
  __syncthreads();
  #pragma unroll
  for (int i = 0; i < 16; i++){
    int idx = i * 256 + t; int d = idx >> 6, p = idx & 63;
    Vt[((long)bh * 64 + d) * 576 + pt * 64 + p] = f2bf(tile[p][d]);
  }
}

// ---------------- attention: one block = one (bh, 16-q-row tile) ----------------
__global__ __launch_bounds__(256) void attn_k(const unsigned short* __restrict__ Qn,
                                              const unsigned short* __restrict__ Kn,
                                              const unsigned short* __restrict__ Vt,
                                              float* __restrict__ O){
  const int qb = blockIdx.x;
  const int bh = blockIdx.y;
  const int b = bh >> 4, h = bh & 15;
  const int tid = threadIdx.x, wv = tid >> 6, lane = tid & 63;
  const int fr = lane & 15, fq = lane >> 4;
  __shared__ float S[16][578];
  __shared__ __align__(16) unsigned short Pl[16][584];

  const unsigned short* qbase = Qn + ((long)bh * 576 + qb * 16 + fr) * 64;
  frag8 qf0 = *(const frag8*)(qbase + fq * 8);
  frag8 qf1 = *(const frag8*)(qbase + 32 + fq * 8);

  for (int i = 0; i < 9; i++){
    const int kt = wv + 4 * i;
    const unsigned short* kbase = Kn + ((long)bh * 576 + kt * 16 + fr) * 64;
    frag8 kf0 = *(const frag8*)(kbase + fq * 8);
    frag8 kf1 = *(const frag8*)(kbase + 32 + fq * 8);
    accf4 a = {0.f, 0.f, 0.f, 0.f};
    a = __builtin_amdgcn_mfma_f32_16x16x32_bf16(qf0, kf0, a, 0, 0, 0);
    a = __builtin_amdgcn_mfma_f32_16x16x32_bf16(qf1, kf1, a, 0, 0, 0);
    #pragma unroll
    for (int rr = 0; rr < 4; rr++) S[fq * 4 + rr][kt * 16 + fr] = a[rr];
  }
  __syncthreads();

  {
    const int row = tid >> 4, cid = tid & 15;
    float vals[36];
    float mx = -1e30f;
    #pragma unroll
    for (int i = 0; i < 36; i++){ vals[i] = S[row][cid + 16 * i]; mx = fmaxf(mx, vals[i]); }
    #pragma unroll
    for (int o = 8; o; o >>= 1) mx = fmaxf(mx, __shfl_xor(mx, o));
    float sum = 0.f;
    #pragma unroll
    for (int i = 0; i < 36; i++){ vals[i] = __expf(vals[i] - mx); sum += vals[i]; }
    #pragma unroll
    for (int o = 8; o; o >>= 1) sum += __shfl_xor(sum, o);
    const float rsum = 1.f / sum;
    #pragma unroll
    for (int i = 0; i < 36; i++) Pl[row][cid + 16 * i] = f2bf(vals[i] * rsum);
  }
  __syncthreads();

  accf4 oa = {0.f, 0.f, 0.f, 0.f};
  for (int kt = 0; kt < 18; kt++){
    frag8 pf = *(const frag8*)&Pl[fr][kt * 32 + fq * 8];
    const unsigned short* vb = Vt + ((long)bh * 64 + wv * 16 + fr) * 576 + kt * 32 + fq * 8;
    frag8 vf = *(const frag8*)vb;
    oa = __builtin_amdgcn_mfma_f32_16x16x32_bf16(pf, vf, oa, 0, 0, 0);
  }
  #pragma unroll
  for (int rr = 0; rr < 4; rr++){
    const long orow = (long)b * 576 + qb * 16 + fq * 4 + rr;
    O[orow * 1024 + h * 64 + wv * 16 + fr] = oa[rr];
  }
}

// ---------------- 128x128 GEMM, depth-2 counted-vmcnt pipeline + T2 k-chunk swizzle ----------------
// LDS layout: k-chunk kq of row r stored at byte r*64 + (kq ^ ((r>>1)&3))*16.
// Staging: inverse-permute the GLOBAL k-offset (LDS dest stays gload16-linear, rule #21).
// Reads: fq' = fq ^ ((fr>>1)&3) -> max 2-way bank alias (free, m136).
// EPI 2: Cb = bf16(gelu(acc+bias)).
// EPI 3: QKV — fused per-head QK-LayerNorm (Q scaled 0.125) -> Qn/Kn bf16; V -> Vf f32.
template<int EPI>
__global__ __launch_bounds__(256) void gemm_bt(
    const unsigned short* __restrict__ A, const unsigned short* __restrict__ Bt,
    float* __restrict__ Cf, unsigned short* __restrict__ Cb,
    const float* __restrict__ bias, const float* __restrict__ ls,
    const float* __restrict__ resid,
    const float* __restrict__ qg, const float* __restrict__ qb2,
    const float* __restrict__ kg, const float* __restrict__ kb2,
    unsigned short* __restrict__ Qn, unsigned short* __restrict__ Kn,
    float* __restrict__ Vf,
    int M, int N, int K, int gx)
{
  __shared__ __align__(16) unsigned short As[3][128 * 32];
  __shared__ __align__(16) unsigned short Bs[3][128 * 32];
  const int tid = threadIdx.x;
  const int wave = tid >> 6, lane = tid & 63;
  const int fr = lane & 15, fq = lane >> 4;
  const int wr = wave >> 1, wc = wave & 1;
  const int fqs = (fq ^ ((fr >> 1) & 3)) * 8;   // T2 read swizzle (elements)
  int tx, ty;
  block_map(blockIdx.x, gridDim.x, gx, tx, ty);
  const long rowbase = (long)ty * 128;
  const long colbase = (long)tx * 128;

  accf4 acc[4][4];
  const accf4 zero = {0.f, 0.f, 0.f, 0.f};
  #pragma unroll
  for (int m = 0; m < 4; m++)
    #pragma unroll
    for (int n = 0; n < 4; n++) acc[m][n] = zero;

  // staging source: k-chunk inverse-permuted to match read swizzle
  const int kq = (tid & 3) ^ ((tid >> 3) & 3);
  const unsigned short* a0 = A + (rowbase + (tid >> 2)) * (long)K + kq * 8;
  const unsigned short* a1 = a0 + 64l * K;
  const unsigned short* b0 = Bt + (colbase + (tid >> 2)) * (long)K + kq * 8;
  const unsigned short* b1 = b0 + 64l * K;

  auto stage = [&](int d, int t){
    const int k0 = t << 5;
    gload16(a0 + k0, &As[d][wave * 512]);
    gload16(a1 + k0, &As[d][2048 + wave * 512]);
    gload16(b0 + k0, &Bs[d][wave * 512]);
    gload16(b1 + k0, &Bs[d][2048 + wave * 512]);
  };
  auto compute = [&](int d){
    frag8 af[4], bf[4];
    #pragma unroll
    for (int m = 0; m < 4; m++) af[m] = *(const frag8*)&As[d][(wr*64 + m*16 + fr)*32 + fqs];
    #pragma unroll
    for (int n = 0; n < 4; n++) bf[n] = *(const frag8*)&Bs[d][(wc*64 + n*16 + fr)*32 + fqs];
    #pragma unroll
    for (int m = 0; m < 4; m++)
      #pragma unroll
      for (int n = 0; n < 4; n++)
        acc[m][n] = __builtin_amdgcn_mfma_f32_16x16x32_bf16(af[m], bf[n], acc[m][n], 0, 0, 0);
  };

  const int NT = K >> 5;
  stage(0, 0);
  stage(1, 1);
  int cur = 0;
  for (int t = 0; t < NT; ++t){
    if (t + 2 < NT) asm volatile("s_waitcnt vmcnt(4)" ::: "memory");
    else            asm volatile("s_waitcnt vmcnt(0)" ::: "memory");
    __builtin_amdgcn_s_barrier();
    __builtin_amdgcn_sched_barrier(0);
    if (t + 2 < NT){
      int nb = cur + 2; if (nb >= 3) nb -= 3;
      stage(nb, t + 2);
    }
    compute(cur);
    cur = cur + 1; if (cur == 3) cur = 0;
    __builtin_amdgcn_s_barrier();
    __builtin_amdgcn_sched_barrier(0);
  }

  if constexpr (EPI == 3){
    // wave owns a 64-row x 64-col tile; 64-col group = one head of one kind
    const int cg = (int)colbase + wc * 64;       // multiple of 64
    const int kind = cg >> 10;                   // 0=Q, 1=K, 2=V
    const int h = (cg & 1023) >> 6;
    if (kind < 2){
      const float* g  = kind ? kg : qg;
      const float* bb = kind ? kb2 : qb2;
      const float sc = kind ? 1.0f : 0.125f;
      unsigned short* Out = kind ? Kn : Qn;
      #pragma unroll
      for (int m = 0; m < 4; m++){
        #pragma unroll
        for (int r = 0; r < 4; r++){
          float s1 = 0.f, s2 = 0.f;
          #pragma unroll
          for (int n = 0; n < 4; n++){ const float v = acc[m][n][r]; s1 += v; s2 += v*v; }
          #pragma unroll
          for (int o = 8; o; o >>= 1){ s1 += __shfl_xor(s1, o); s2 += __shfl_xor(s2, o); }
          const float mean = s1 * (1.f/64.f);
          const float inv = rsqrtf(s2 * (1.f/64.f) - mean*mean + 1e-6f);
          const long row = rowbase + wr*64 + m*16 + fq*4 + r;
          const int bq = (int)(row / 576), p = (int)(row - (long)bq*576);
          unsigned short* dst = Out + (((long)(bq*16 + h))*576 + p)*64;
          #pragma unroll
          for (int n = 0; n < 4; n++){
            const int d = n*16 + fr;
            dst[d] = f2bf(((acc[m][n][r] - mean)*inv*g[d] + bb[d]) * sc);
          }
        }
      }
    } else {
      // V third: plain f32 into Vf [4608][1024]
      #pragma unroll
      for (int m = 0; m < 4; m++){
        const long rb = rowbase + wr*64 + m*16 + fq*4;
        #pragma unroll
        for (int n = 0; n < 4; n++){
          const int vc = (cg - 2048) + n*16 + fr;
          #pragma unroll
          for (int r = 0; r < 4; r++)
            Vf[(rb + r)*1024 + vc] = acc[m][n][r];
        }
      }
    }
  } else {
    #pragma unroll
    for (int m = 0; m < 4; m++){
      const long rb = rowbase + wr * 64 + m * 16 + fq * 4;
      #pragma unroll
      for (int n = 0; n < 4; n++){
        const long cb = colbase + wc * 64 + n * 16 + fr;
        #pragma unroll
        for (int r = 0; r < 4; r++){
          const long idx = (rb + r) * N + cb;
          const float v = acc[m][n][r];
          if constexpr (EPI == 1){
            Cf[idx] = resid[idx] + (v + bias[cb]) * ls[cb];
          } else {
            Cb[idx] = f2bf(gelu_tanh(v + bias[cb]));
          }
        }
      }
    }
  }
}

// ---------------- 128x64 GEMM, depth-2 counted-vmcnt pipeline + T2, EPI1 ----------------
__global__ __launch_bounds__(256) void gemm_n64(
    const unsigned short* __restrict__ A, const unsigned short* __restrict__ Bt,
    float* __restrict__ Cf,
    const float* __restrict__ bias, const float* __restrict__ ls,
    const float* __restrict__ resid, int M, int N, int K, int gx)
{
  __shared__ __align__(16) unsigned short As[3][128 * 32];
  __shared__ __align__(16) unsigned short Bs[3][64 * 32];
  const int tid = threadIdx.x;
  const int wave = tid >> 6, lane = tid & 63;
  const int fr = lane & 15, fq = lane >> 4;
  const int wr = wave >> 1, wc = wave & 1;
  const int fqs = (fq ^ ((fr >> 1) & 3)) * 8;
  int tx, ty;
  block_map(blockIdx.x, gridDim.x, gx, tx, ty);
  const long rowbase = (long)ty * 128;
  const long colbase = (long)tx * 64;

  accf4 acc[4][2];
  const accf4 zero = {0.f, 0.f, 0.f, 0.f};
  #pragma unroll
  for (int m = 0; m < 4; m++){ acc[m][0] = zero; acc[m][1] = zero; }

  const int kq = (tid & 3) ^ ((tid >> 3) & 3);
  const unsigned short* a0 = A + (rowbase + (tid >> 2)) * (long)K + kq * 8;
  const unsigned short* a1 = a0 + 64l * K;
  const unsigned short* b0 = Bt + (colbase + (tid >> 2)) * (long)K + kq * 8;

  auto stage = [&](int d, int t){
    const int k0 = t << 5;
    gload16(a0 + k0, &As[d][wave * 512]);
    gload16(a1 + k0, &As[d][2048 + wave * 512]);
    gload16(b0 + k0, &Bs[d][wave * 512]);
  };
  auto compute = [&](int d){
    frag8 af[4], bf[2];
    #pragma unroll
    for (int m = 0; m < 4; m++) af[m] = *(const frag8*)&As[d][(wr*64 + m*16 + fr)*32 + fqs];
    #pragma unroll
    for (int n = 0; n < 2; n++) bf[n] = *(const frag8*)&Bs[d][(wc*32 + n*16 + fr)*32 + fqs];
    #pragma unroll
    for (int m = 0; m < 4; m++)
      #pragma unroll
      for (int n = 0; n < 2; n++)
        acc[m][n] = __builtin_amdgcn_mfma_f32_16x16x32_bf16(af[m], bf[n], acc[m][n], 0, 0, 0);
  };

  const int NT = K >> 5;
  stage(0, 0);
  stage(1, 1);
  int cur = 0;
  for (int t = 0; t < NT; ++t){
    if (t + 2 < NT) asm volatile("s_waitcnt vmcnt(3)" ::: "memory");
    else            asm volatile("s_waitcnt vmcnt(0)" ::: "memory");
    __builtin_amdgcn_s_barrier();
    __builtin_amdgcn_sched_barrier(0);
    if (t + 2 < NT){
      int nb = cur + 2; if (nb >= 3) nb -= 3;
      stage(nb, t + 2);
    }
    compute(cur);
    cur = cur + 1; if (cur == 3) cur = 0;
    __builtin_amdgcn_s_barrier();
    __builtin_amdgcn_sched_barrier(0);
  }

  #pragma unroll
  for (int m = 0; m < 4; m++){
    const long rb = rowbase + wr * 64 + m * 16 + fq * 4;
    #pragma unroll
    for (int n = 0; n < 2; n++){
      const long cb = colbase + wc * 32 + n * 16 + fr;
      #pragma unroll
      for (int r = 0; r < 4; r++){
        const long idx = (rb + r) * N + cb;
        Cf[idx] = resid[idx] + (acc[m][n][r] + bias[cb]) * ls[cb];
      }
    }
  }
}

extern "C" void kernel_launch(void* const* d_in, const int* in_sizes, int n_in,
                              void* d_out, int out_size, void* d_ws, size_t ws_size,
                              hipStream_t stream){
  (void)in_sizes; (void)n_in; (void)out_size; (void)ws_size;
  const float* x      = (const float*)d_in[0];
  const float* w_qkv  = (const float*)d_in[1];
  const float* q_g    = (const float*)d_in[2];
  const float* q_b    = (const float*)d_in[3];
  const float* k_g    = (const float*)d_in[4];
  const float* k_b    = (const float*)d_in[5];
  const float* o_g    = (const float*)d_in[6];
  const float* o_b    = (const float*)d_in[7];
  const float* w_proj = (const float*)d_in[8];
  const float* b_proj = (const float*)d_in[9];
  const float* ln1_g  = (const float*)d_in[10];
  const float* ln1_b  = (const float*)d_in[11];
  const float* ln2_g  = (const float*)d_in[12];
  const float* ln2_b  = (const float*)d_in[13];
  const float* w1     = (const float*)d_in[14];
  const float* b1     = (const float*)d_in[15];
  const float* w2     = (const float*)d_in[16];
  const float* b2     = (const float*)d_in[17];
  const float* ls1    = (const float*)d_in[18];
  const float* ls2    = (const float*)d_in[19];
  float* out = (float*)d_out;

  char* ws = (char*)d_ws;
  size_t off = 0;
  auto alloc = [&](size_t bytes)->void*{
    void* p = ws + off; off += (bytes + 255) & ~(size_t)255; return p;
  };
  unsigned short* wqkvT  = (unsigned short*)alloc(3072l*1024*2);
  unsigned short* wprojT = (unsigned short*)alloc(1024l*1024*2);
  unsigned short* w1T    = (unsigned short*)alloc(4096l*1024*2);
  unsigned short* w2T    = (unsigned short*)alloc(1024l*4096*2);
  unsigned short* xnA    = (unsigned short*)alloc(4608l*1024*2);   // xn1 / on / xn2
  float*          qkvVf  = (float*)alloc(4608l*1024*4);            // V third, f32
  unsigned short* Qn     = (unsigned short*)alloc(73728l*64*2);
  unsigned short* Kn     = (unsigned short*)alloc(73728l*64*2);
  unsigned short* Vt     = (unsigned short*)alloc(73728l*64*2);
  unsigned short* hbf    = (unsigned short*)alloc(4608l*4096*2);
  float*          attnO  = qkvVf;   // overlay: qkvVf dead after v_trans

  // weights -> bf16 B^T
  wtrans<<<dim3(3072/32, 1024/32), dim3(32,8), 0, stream>>>(w_qkv,  wqkvT,  1024, 3072);
  wtrans<<<dim3(1024/32, 1024/32), dim3(32,8), 0, stream>>>(w_proj, wprojT, 1024, 1024);
  wtrans<<<dim3(4096/32, 1024/32), dim3(32,8), 0, stream>>>(w1,     w1T,    1024, 4096);
  wtrans<<<dim3(1024/32, 4096/32), dim3(32,8), 0, stream>>>(w2,     w2T,    4096, 1024);

  // attention branch
  ln_rows<<<4608, 256, 0, stream>>>(x, ln1_g, ln1_b, xnA);
  gemm_bt<3><<<24*36, 256, 0, stream>>>(xnA, wqkvT, nullptr, nullptr,
                                        nullptr, nullptr, nullptr,
                                        q_g, q_b, k_g, k_b, Qn, Kn, qkvVf,
                                        4608, 3072, 1024, 24);
  v_trans<<<dim3(128,9), 256, 0, stream>>>(qkvVf, Vt);
  attn_k<<<dim3(36,128), 256, 0, stream>>>(Qn, Kn, Vt, attnO);
  ln_rows<<<4608, 256, 0, stream>>>(attnO, o_g, o_b, xnA);
  gemm_n64<<<16*36, 256, 0, stream>>>(xnA, wprojT, out, b_proj, ls1, x,
                                      4608, 1024, 1024, 16);
  // MLP branch
  ln_rows<<<4608, 256, 0, stream>>>(out, ln2_g, ln2_b, xnA);
  gemm_bt<2><<<32*36, 256, 0, stream>>>(xnA, w1T, nullptr, hbf,
                                        b1, nullptr, nullptr,
                                        nullptr, nullptr, nullptr, nullptr,
                                        nullptr, nullptr, nullptr,
                                        4608, 4096, 1024, 32);
  gemm_n64<<<16*36, 256, 0, stream>>>(hbf, w2T, out, b2, ls2, out,
                                      4608, 1024, 4096, 16);
}

// Round 11
// 326.716 us; speedup vs baseline: 1.1999x; 1.0363x over previous
//
#include <hip/hip_runtime.h>
#include <hip/hip_bf16.h>

#define DEV static __device__ __forceinline__

typedef short frag8 __attribute__((ext_vector_type(8)));
typedef float accf4 __attribute__((ext_vector_type(4)));

// Problem constants: B=8, P=576, D=1024, H=16, HD=64, HID=4096, BP=4608, BH=128

DEV unsigned short f2bf(float f){
  union { float f; unsigned int u; } v; v.f = f;
  unsigned int r = v.u + 0x7fffu + ((v.u >> 16) & 1u);
  return (unsigned short)(r >> 16);
}

DEV void gload16(const void* g, void* l){
  __builtin_amdgcn_global_load_lds((const __attribute__((address_space(1))) void*)g,
                                   (__attribute__((address_space(3))) void*)l, 16, 0, 0);
}

DEV float gelu_tanh(float x){
  float u = 0.7978845608028654f * (x + 0.044715f * x * x * x);
  float e = __expf(2.0f * u);
  float th = 1.0f - 2.0f / (e + 1.0f);   // tanh(u), inf-safe
  return 0.5f * x * (1.0f + th);
}

// T1 XCD chunking + GW=16 column-grouped within-chunk mapping.
DEV void block_map(int bid, int nwg, int gx, int& tx, int& ty){
  const int swz = ((nwg & 7) == 0) ? ((bid & 7) * (nwg >> 3) + (bid >> 3)) : bid;
  const int gy = nwg / gx;
  const int cg = swz / (gy * 16);
  const int rr = swz - cg * gy * 16;
  const int gw = min(16, gx - cg * 16);
  tx = cg * 16 + rr % gw;
  ty = rr / gw;
}

// ---------------- weight cast + transpose: W[K,N] f32 -> Wt[N,K] bf16 ----------------
__global__ __launch_bounds__(256) void wtrans(const float* __restrict__ W,
                                              unsigned short* __restrict__ Wt,
                                              int K, int N){
  __shared__ float t[32][33];
  const int n0 = blockIdx.x * 32, k0 = blockIdx.y * 32;
  const int tx = threadIdx.x, ty = threadIdx.y;   // (32,8)
  #pragma unroll
  for (int i = 0; i < 4; i++)
    t[ty + i*8][tx] = W[(long)(k0 + ty + i*8) * N + n0 + tx];
  __syncthreads();
  #pragma unroll
  for (int i = 0; i < 4; i++)
    Wt[(long)(n0 + ty + i*8) * K + k0 + tx] = f2bf(t[tx][ty + i*8]);
}

// ---------------- LayerNorm over D=1024 rows: f32 in -> bf16 out ----------------
__global__ __launch_bounds__(256) void ln_rows(const float* __restrict__ in,
                                               const float* __restrict__ g,
                                               const float* __restrict__ beta,
                                               unsigned short* __restrict__ out){
  const long row = blockIdx.x;
  const int t = threadIdx.x;
  const float4 v = ((const float4*)(in + row * 1024))[t];
  float s  = v.x + v.y + v.z + v.w;
  float s2 = v.x*v.x + v.y*v.y + v.z*v.z + v.w*v.w;
  #pragma unroll
  for (int o = 32; o; o >>= 1){ s += __shfl_xor(s, o); s2 += __shfl_xor(s2, o); }
  __shared__ float rs[4], rq[4];
  const int wv = t >> 6;
  if ((t & 63) == 0){ rs[wv] = s; rq[wv] = s2; }
  __syncthreads();
  s  = rs[0] + rs[1] + rs[2] + rs[3];
  s2 = rq[0] + rq[1] + rq[2] + rq[3];
  const float mean = s * (1.f/1024.f);
  const float inv = rsqrtf(s2 * (1.f/1024.f) - mean*mean + 1e-6f);
  const float4 gv = ((const float4*)g)[t];
  const float4 bv = ((const float4*)beta)[t];
  ushort4 o4;
  o4.x = f2bf((v.x - mean)*inv*gv.x + bv.x);
  o4.y = f2bf((v.y - mean)*inv*gv.y + bv.y);
  o4.z = f2bf((v.z - mean)*inv*gv.z + bv.z);
  o4.w = f2bf((v.w - mean)*inv*gv.w + bv.w);
  *(ushort4*)(out + row * 1024 + t * 4) = o4;
}

// ---------------- V transpose per head: qkvVf [4608][1024] f32 -> Vt [BH][64][576] bf16 ----------------
__global__ __launch_bounds__(256) void v_trans(const float* __restrict__ qkvVf,
                                               unsigned short* __restrict__ Vt){
  const int bh = blockIdx.x, pt = blockIdx.y;   // pt: 0..8 (64 p's each)
  const int b = bh >> 4, h = bh & 15;
  __shared__ float tile[64][65];
  const int t = threadIdx.x;
  #pragma unroll
  for (int i = 0; i < 16; i++){
    int idx = i * 256 + t; int p = idx >> 6, d = idx & 63;
    tile[p][d] = qkvVf[((long)(b * 576) + pt * 64 + p) * 1024 + h * 64 + d];
  }
  __syncthreads();
  #pragma unroll
  for (int i = 0; i < 16; i++){
    int idx = i * 256 + t; int d = idx >> 6, p = idx & 63;
    Vt[((long)bh * 64 + d) * 576 + pt * 64 + p] = f2bf(tile[p][d]);
  }
}

// ---------------- attention: one block = one (bh, 16-q-row tile) ----------------
__global__ __launch_bounds__(256) void attn_k(const unsigned short* __restrict__ Qn,
                                              const unsigned short* __restrict__ Kn,
                                              const unsigned short* __restrict__ Vt,
                                              float* __restrict__ O){
  const int qb = blockIdx.x;
  const int bh = blockIdx.y;
  const int b = bh >> 4, h = bh & 15;
  const int tid = threadIdx.x, wv = tid >> 6, lane = tid & 63;
  const int fr = lane & 15, fq = lane >> 4;
  __shared__ float S[16][578];
  __shared__ __align__(16) unsigned short Pl[16][584];

  const unsigned short* qbase = Qn + ((long)bh * 576 + qb * 16 + fr) * 64;
  frag8 qf0 = *(const frag8*)(qbase + fq * 8);
  frag8 qf1 = *(const frag8*)(qbase + 32 + fq * 8);

  for (int i = 0; i < 9; i++){
    const int kt = wv + 4 * i;
    const unsigned short* kbase = Kn + ((long)bh * 576 + kt * 16 + fr) * 64;
    frag8 kf0 = *(const frag8*)(kbase + fq * 8);
    frag8 kf1 = *(const frag8*)(kbase + 32 + fq * 8);
    accf4 a = {0.f, 0.f, 0.f, 0.f};
    a = __builtin_amdgcn_mfma_f32_16x16x32_bf16(qf0, kf0, a, 0, 0, 0);
    a = __builtin_amdgcn_mfma_f32_16x16x32_bf16(qf1, kf1, a, 0, 0, 0);
    #pragma unroll
    for (int rr = 0; rr < 4; rr++) S[fq * 4 + rr][kt * 16 + fr] = a[rr];
  }
  __syncthreads();

  {
    const int row = tid >> 4, cid = tid & 15;
    float vals[36];
    float mx = -1e30f;
    #pragma unroll
    for (int i = 0; i < 36; i++){ vals[i] = S[row][cid + 16 * i]; mx = fmaxf(mx, vals[i]); }
    #pragma unroll
    for (int o = 8; o; o >>= 1) mx = fmaxf(mx, __shfl_xor(mx, o));
    float sum = 0.f;
    #pragma unroll
    for (int i = 0; i < 36; i++){ vals[i] = __expf(vals[i] - mx); sum += vals[i]; }
    #pragma unroll
    for (int o = 8; o; o >>= 1) sum += __shfl_xor(sum, o);
    const float rsum = 1.f / sum;
    #pragma unroll
    for (int i = 0; i < 36; i++) Pl[row][cid + 16 * i] = f2bf(vals[i] * rsum);
  }
  __syncthreads();

  accf4 oa = {0.f, 0.f, 0.f, 0.f};
  for (int kt = 0; kt < 18; kt++){
    frag8 pf = *(const frag8*)&Pl[fr][kt * 32 + fq * 8];
    const unsigned short* vb = Vt + ((long)bh * 64 + wv * 16 + fr) * 576 + kt * 32 + fq * 8;
    frag8 vf = *(const frag8*)vb;
    oa = __builtin_amdgcn_mfma_f32_16x16x32_bf16(pf, vf, oa, 0, 0, 0);
  }
  #pragma unroll
  for (int rr = 0; rr < 4; rr++){
    const long orow = (long)b * 576 + qb * 16 + fq * 4 + rr;
    O[orow * 1024 + h * 64 + wv * 16 + fr] = oa[rr];
  }
}

// ---------------- 256x256 8-wave BK=64 GEMM, minimum-2-phase (T3 recipe), fused QK-LN ----------------
// stage(t+1) issued BEFORE compute(t); ONE __syncthreads per K-step (vmcnt0+lgkm0+barrier).
// T2: k-chunk c stored at c^(row&7) (inverse on global source; LDS dest linear).
// Epilogue: per-head QK-LayerNorm (Q scaled 0.125) -> Qn/Kn bf16; V -> Vf f32.
__global__ __launch_bounds__(512) void gemm256(
    const unsigned short* __restrict__ Ag, const unsigned short* __restrict__ Btg,
    const float* __restrict__ qg, const float* __restrict__ qb2,
    const float* __restrict__ kg, const float* __restrict__ kb2,
    unsigned short* __restrict__ Qn, unsigned short* __restrict__ Kn,
    float* __restrict__ Vf, int K, int gx)
{
  __shared__ __align__(16) unsigned short As[2][256 * 64];   // 32 KB per buffer
  __shared__ __align__(16) unsigned short Bs[2][256 * 64];
  const int tid = threadIdx.x;
  const int w = tid >> 6, l = tid & 63;
  const int fr = l & 15, fq = l >> 4;
  const int wr = w >> 2, wc = w & 3;          // 2 x 4 wave grid, wave tile 128x64
  const int rsw = fr & 7;                     // T2 read swizzle mask
  const int nwg = gridDim.x, bid = blockIdx.x;
  const int swz = ((nwg & 7) == 0) ? ((bid & 7) * (nwg >> 3) + (bid >> 3)) : bid;
  const int tx = swz % gx, ty = swz / gx;
  const long rowbase = (long)ty * 256;
  const long colbase = (long)tx * 256;

  // staging constants: wave w, slot s covers rows w*32 + s*8 + (l>>3), chunk (l&7)
  const int r8 = l >> 3;
  const int kq = (l & 7) ^ r8;                // inverse-swizzled source k-chunk
  const unsigned short* aS = Ag + (rowbase + w*32 + r8) * (long)K + kq * 8;
  const unsigned short* bS = Btg + (colbase + w*32 + r8) * (long)K + kq * 8;

  accf4 acc[8][4];
  const accf4 zero = {0.f, 0.f, 0.f, 0.f};
  #pragma unroll
  for (int m = 0; m < 8; m++)
    #pragma unroll
    for (int n = 0; n < 4; n++) acc[m][n] = zero;

  auto stage = [&](int d, int t){
    const long k0 = (long)t * 64;
    #pragma unroll
    for (int s = 0; s < 4; s++)
      gload16(aS + (long)s * 8 * K + k0, &As[d][w * 2048 + s * 512]);
    #pragma unroll
    for (int s = 0; s < 4; s++)
      gload16(bS + (long)s * 8 * K + k0, &Bs[d][w * 2048 + s * 512]);
  };
  auto compute = [&](int d){
    #pragma unroll
    for (int kk = 0; kk < 2; kk++){
      const int csw = ((kk * 4 + fq) ^ rsw) * 8;
      frag8 bf[4];
      #pragma unroll
      for (int nj = 0; nj < 4; nj++)
        bf[nj] = *(const frag8*)&Bs[d][(wc*64 + nj*16 + fr) * 64 + csw];
      #pragma unroll
      for (int mi = 0; mi < 8; mi++){
        frag8 af = *(const frag8*)&As[d][(wr*128 + mi*16 + fr) * 64 + csw];
        #pragma unroll
        for (int nj = 0; nj < 4; nj++)
          acc[mi][nj] = __builtin_amdgcn_mfma_f32_16x16x32_bf16(af, bf[nj], acc[mi][nj], 0, 0, 0);
      }
    }
  };

  const int NT = K >> 6;
  stage(0, 0);
  __syncthreads();
  int cur = 0;
  for (int t = 0; t < NT; ++t){
    if (t + 1 < NT) stage(cur ^ 1, t + 1);
    compute(cur);
    __syncthreads();
    cur ^= 1;
  }

  // epilogue: wave owns 128 rows x 64 cols; 64-col group = one head of one kind
  const int cg = (int)colbase + wc * 64;
  const int kind = cg >> 10;                   // 0=Q, 1=K, 2=V
  if (kind < 2){
    const float* g  = kind ? kg : qg;
    const float* bb = kind ? kb2 : qb2;
    const float sc = kind ? 1.0f : 0.125f;
    unsigned short* Out = kind ? Kn : Qn;
    const int h = (cg & 1023) >> 6;
    #pragma unroll
    for (int mi = 0; mi < 8; mi++){
      #pragma unroll
      for (int r = 0; r < 4; r++){
        float s1 = 0.f, s2 = 0.f;
        #pragma unroll
        for (int nj = 0; nj < 4; nj++){ const float v = acc[mi][nj][r]; s1 += v; s2 += v*v; }
        #pragma unroll
        for (int o = 8; o; o >>= 1){ s1 += __shfl_xor(s1, o); s2 += __shfl_xor(s2, o); }
        const float mean = s1 * (1.f/64.f);
        const float inv = rsqrtf(s2 * (1.f/64.f) - mean*mean + 1e-6f);
        const long row = rowbase + wr*128 + mi*16 + fq*4 + r;
        const int bq = (int)(row / 576), p = (int)(row - (long)bq*576);
        unsigned short* dst = Out + (((long)(bq*16 + h))*576 + p)*64;
        #pragma unroll
        for (int nj = 0; nj < 4; nj++){
          const int d = nj*16 + fr;
          dst[d] = f2bf(((acc[mi][nj][r] - mean)*inv*g[d] + bb[d]) * sc);
        }
      }
    }
  } else {
    #pragma unroll
    for (int mi = 0; mi < 8; mi++){
      const long rb = rowbase + wr*128 + mi*16 + fq*4;
      #pragma unroll
      for (int nj = 0; nj < 4; nj++){
        const int vc = (cg - 2048) + nj*16 + fr;
        #pragma unroll
        for (int r = 0; r < 4; r++)
          Vf[(rb + r)*1024 + vc] = acc[mi][nj][r];
      }
    }
  }
}

// ---------------- 128x128 GEMM, depth-2 counted-vmcnt pipeline + T2 (MLP1) ----------------
// EPI 2: Cb = bf16(gelu(acc+bias)).
template<int EPI>
__global__ __launch_bounds__(256) void gemm_bt(
    const unsigned short* __restrict__ A, const unsigned short* __restrict__ Bt,
    float* __restrict__ Cf, unsigned short* __restrict__ Cb,
    const float* __restrict__ bias, const float* __restrict__ ls,
    const float* __restrict__ resid, int M, int N, int K, int gx)
{
  __shared__ __align__(16) unsigned short As[3][128 * 32];
  __shared__ __align__(16) unsigned short Bs[3][128 * 32];
  const int tid = threadIdx.x;
  const int wave = tid >> 6, lane = tid & 63;
  const int fr = lane & 15, fq = lane >> 4;
  const int wr = wave >> 1, wc = wave & 1;
  const int fqs = (fq ^ ((fr >> 1) & 3)) * 8;   // T2 read swizzle (elements)
  int tx, ty;
  block_map(blockIdx.x, gridDim.x, gx, tx, ty);
  const long rowbase = (long)ty * 128;
  const long colbase = (long)tx * 128;

  accf4 acc[4][4];
  const accf4 zero = {0.f, 0.f, 0.f, 0.f};
  #pragma unroll
  for (int m = 0; m < 4; m++)
    #pragma unroll
    for (int n = 0; n < 4; n++) acc[m][n] = zero;

  const int kq = (tid & 3) ^ ((tid >> 3) & 3);
  const unsigned short* a0 = A + (rowbase + (tid >> 2)) * (long)K + kq * 8;
  const unsigned short* a1 = a0 + 64l * K;
  const unsigned short* b0 = Bt + (colbase + (tid >> 2)) * (long)K + kq * 8;
  const unsigned short* b1 = b0 + 64l * K;

  auto stage = [&](int d, int t){
    const int k0 = t << 5;
    gload16(a0 + k0, &As[d][wave * 512]);
    gload16(a1 + k0, &As[d][2048 + wave * 512]);
    gload16(b0 + k0, &Bs[d][wave * 512]);
    gload16(b1 + k0, &Bs[d][2048 + wave * 512]);
  };
  auto compute = [&](int d){
    frag8 af[4], bf[4];
    #pragma unroll
    for (int m = 0; m < 4; m++) af[m] = *(const frag8*)&As[d][(wr*64 + m*16 + fr)*32 + fqs];
    #pragma unroll
    for (int n = 0; n < 4; n++) bf[n] = *(const frag8*)&Bs[d][(wc*64 + n*16 + fr)*32 + fqs];
    #pragma unroll
    for (int m = 0; m < 4; m++)
      #pragma unroll
      for (int n = 0; n < 4; n++)
        acc[m][n] = __builtin_amdgcn_mfma_f32_16x16x32_bf16(af[m], bf[n], acc[m][n], 0, 0, 0);
  };

  const int NT = K >> 5;
  stage(0, 0);
  stage(1, 1);
  int cur = 0;
  for (int t = 0; t < NT; ++t){
    if (t + 2 < NT) asm volatile("s_waitcnt vmcnt(4)" ::: "memory");
    else            asm volatile("s_waitcnt vmcnt(0)" ::: "memory");
    __builtin_amdgcn_s_barrier();
    __builtin_amdgcn_sched_barrier(0);
    if (t + 2 < NT){
      int nb = cur + 2; if (nb >= 3) nb -= 3;
      stage(nb, t + 2);
    }
    compute(cur);
    cur = cur + 1; if (cur == 3) cur = 0;
    __builtin_amdgcn_s_barrier();
    __builtin_amdgcn_sched_barrier(0);
  }

  #pragma unroll
  for (int m = 0; m < 4; m++){
    const long rb = rowbase + wr * 64 + m * 16 + fq * 4;
    #pragma unroll
    for (int n = 0; n < 4; n++){
      const long cb = colbase + wc * 64 + n * 16 + fr;
      #pragma unroll
      for (int r = 0; r < 4; r++){
        const long idx = (rb + r) * N + cb;
        const float v = acc[m][n][r];
        if constexpr (EPI == 1){
          Cf[idx] = resid[idx] + (v + bias[cb]) * ls[cb];
        } else {
          Cb[idx] = f2bf(gelu_tanh(v + bias[cb]));
        }
      }
    }
  }
}

// ---------------- 128x64 GEMM, depth-2 counted-vmcnt pipeline + T2, EPI1 ----------------
__global__ __launch_bounds__(256) void gemm_n64(
    const unsigned short* __restrict__ A, const unsigned short* __restrict__ Bt,
    float* __restrict__ Cf,
    const float* __restrict__ bias, const float* __restrict__ ls,
    const float* __restrict__ resid, int M, int N, int K, int gx)
{
  __shared__ __align__(16) unsigned short As[3][128 * 32];
  __shared__ __align__(16) unsigned short Bs[3][64 * 32];
  const int tid = threadIdx.x;
  const int wave = tid >> 6, lane = tid & 63;
  const int fr = lane & 15, fq = lane >> 4;
  const int wr = wave >> 1, wc = wave & 1;
  const int fqs = (fq ^ ((fr >> 1) & 3)) * 8;
  int tx, ty;
  block_map(blockIdx.x, gridDim.x, gx, tx, ty);
  const long rowbase = (long)ty * 128;
  const long colbase = (long)tx * 64;

  accf4 acc[4][2];
  const accf4 zero = {0.f, 0.f, 0.f, 0.f};
  #pragma unroll
  for (int m = 0; m < 4; m++){ acc[m][0] = zero; acc[m][1] = zero; }

  const int kq = (tid & 3) ^ ((tid >> 3) & 3);
  const unsigned short* a0 = A + (rowbase + (tid >> 2)) * (long)K + kq * 8;
  const unsigned short* a1 = a0 + 64l * K;
  const unsigned short* b0 = Bt + (colbase + (tid >> 2)) * (long)K + kq * 8;

  auto stage = [&](int d, int t){
    const int k0 = t << 5;
    gload16(a0 + k0, &As[d][wave * 512]);
    gload16(a1 + k0, &As[d][2048 + wave * 512]);
    gload16(b0 + k0, &Bs[d][wave * 512]);
  };
  auto compute = [&](int d){
    frag8 af[4], bf[2];
    #pragma unroll
    for (int m = 0; m < 4; m++) af[m] = *(const frag8*)&As[d][(wr*64 + m*16 + fr)*32 + fqs];
    #pragma unroll
    for (int n = 0; n < 2; n++) bf[n] = *(const frag8*)&Bs[d][(wc*32 + n*16 + fr)*32 + fqs];
    #pragma unroll
    for (int m = 0; m < 4; m++)
      #pragma unroll
      for (int n = 0; n < 2; n++)
        acc[m][n] = __builtin_amdgcn_mfma_f32_16x16x32_bf16(af[m], bf[n], acc[m][n], 0, 0, 0);
  };

  const int NT = K >> 5;
  stage(0, 0);
  stage(1, 1);
  int cur = 0;
  for (int t = 0; t < NT; ++t){
    if (t + 2 < NT) asm volatile("s_waitcnt vmcnt(3)" ::: "memory");
    else            asm volatile("s_waitcnt vmcnt(0)" ::: "memory");
    __builtin_amdgcn_s_barrier();
    __builtin_amdgcn_sched_barrier(0);
    if (t + 2 < NT){
      int nb = cur + 2; if (nb >= 3) nb -= 3;
      stage(nb, t + 2);
    }
    compute(cur);
    cur = cur + 1; if (cur == 3) cur = 0;
    __builtin_amdgcn_s_barrier();
    __builtin_amdgcn_sched_barrier(0);
  }

  #pragma unroll
  for (int m = 0; m < 4; m++){
    const long rb = rowbase + wr * 64 + m * 16 + fq * 4;
    #pragma unroll
    for (int n = 0; n < 2; n++){
      const long cb = colbase + wc * 32 + n * 16 + fr;
      #pragma unroll
      for (int r = 0; r < 4; r++){
        const long idx = (rb + r) * N + cb;
        Cf[idx] = resid[idx] + (acc[m][n][r] + bias[cb]) * ls[cb];
      }
    }
  }
}

extern "C" void kernel_launch(void* const* d_in, const int* in_sizes, int n_in,
                              void* d_out, int out_size, void* d_ws, size_t ws_size,
                              hipStream_t stream){
  (void)in_sizes; (void)n_in; (void)out_size; (void)ws_size;
  const float* x      = (const float*)d_in[0];
  const float* w_qkv  = (const float*)d_in[1];
  const float* q_g    = (const float*)d_in[2];
  const float* q_b    = (const float*)d_in[3];
  const float* k_g    = (const float*)d_in[4];
  const float* k_b    = (const float*)d_in[5];
  const float* o_g    = (const float*)d_in[6];
  const float* o_b    = (const float*)d_in[7];
  const float* w_proj = (const float*)d_in[8];
  const float* b_proj = (const float*)d_in[9];
  const float* ln1_g  = (const float*)d_in[10];
  const float* ln1_b  = (const float*)d_in[11];
  const float* ln2_g  = (const float*)d_in[12];
  const float* ln2_b  = (const float*)d_in[13];
  const float* w1     = (const float*)d_in[14];
  const float* b1     = (const float*)d_in[15];
  const float* w2     = (const float*)d_in[16];
  const float* b2     = (const float*)d_in[17];
  const float* ls1    = (const float*)d_in[18];
  const float* ls2    = (const float*)d_in[19];
  float* out = (float*)d_out;

  char* ws = (char*)d_ws;
  size_t off = 0;
  auto alloc = [&](size_t bytes)->void*{
    void* p = ws + off; off += (bytes + 255) & ~(size_t)255; return p;
  };
  unsigned short* wqkvT  = (unsigned short*)alloc(3072l*1024*2);
  unsigned short* wprojT = (unsigned short*)alloc(1024l*1024*2);
  unsigned short* w1T    = (unsigned short*)alloc(4096l*1024*2);
  unsigned short* w2T    = (unsigned short*)alloc(1024l*4096*2);
  unsigned short* xnA    = (unsigned short*)alloc(4608l*1024*2);   // xn1 / on / xn2
  float*          qkvVf  = (float*)alloc(4608l*1024*4);            // V third, f32
  unsigned short* Qn     = (unsigned short*)alloc(73728l*64*2);
  unsigned short* Kn     = (unsigned short*)alloc(73728l*64*2);
  unsigned short* Vt     = (unsigned short*)alloc(73728l*64*2);
  unsigned short* hbf    = (unsigned short*)alloc(4608l*4096*2);
  float*          attnO  = qkvVf;   // overlay: qkvVf dead after v_trans

  // weights -> bf16 B^T
  wtrans<<<dim3(3072/32, 1024/32), dim3(32,8), 0, stream>>>(w_qkv,  wqkvT,  1024, 3072);
  wtrans<<<dim3(1024/32, 1024/32), dim3(32,8), 0, stream>>>(w_proj, wprojT, 1024, 1024);
  wtrans<<<dim3(4096/32, 1024/32), dim3(32,8), 0, stream>>>(w1,     w1T,    1024, 4096);
  wtrans<<<dim3(1024/32, 4096/32), dim3(32,8), 0, stream>>>(w2,     w2T,    4096, 1024);

  // attention branch
  ln_rows<<<4608, 256, 0, stream>>>(x, ln1_g, ln1_b, xnA);
  gemm256<<<18*12, 512, 0, stream>>>(xnA, wqkvT,
                                     q_g, q_b, k_g, k_b, Qn, Kn, qkvVf,
                                     1024, 12);
  v_trans<<<dim3(128,9), 256, 0, stream>>>(qkvVf, Vt);
  attn_k<<<dim3(36,128), 256, 0, stream>>>(Qn, Kn, Vt, attnO);
  ln_rows<<<4608, 256, 0, stream>>>(attnO, o_g, o_b, xnA);
  gemm_n64<<<16*36, 256, 0, stream>>>(xnA, wprojT, out, b_proj, ls1, x,
                                      4608, 1024, 1024, 16);
  // MLP branch
  ln_rows<<<4608, 256, 0, stream>>>(out, ln2_g, ln2_b, xnA);
  gemm_bt<2><<<32*36, 256, 0, stream>>>(xnA, w1T, nullptr, hbf,
                                        b1, nullptr, nullptr,
                                        4608, 4096, 1024, 32);
  gemm_n64<<<16*36, 256, 0, stream>>>(hbf, w2T, out, b2, ls2, out,
                                      4608, 1024, 4096, 16);
}

// Round 12
// 301.199 us; speedup vs baseline: 1.3016x; 1.0847x over previous
//
#include <hip/hip_runtime.h>
#include <hip/hip_bf16.h>

#define DEV static __device__ __forceinline__

typedef short frag8 __attribute__((ext_vector_type(8)));
typedef float accf4 __attribute__((ext_vector_type(4)));

// Problem constants: B=8, P=576, D=1024, H=16, HD=64, HID=4096, BP=4608, BH=128

DEV unsigned short f2bf(float f){
  union { float f; unsigned int u; } v; v.f = f;
  unsigned int r = v.u + 0x7fffu + ((v.u >> 16) & 1u);
  return (unsigned short)(r >> 16);
}

DEV void gload16(const void* g, void* l){
  __builtin_amdgcn_global_load_lds((const __attribute__((address_space(1))) void*)g,
                                   (__attribute__((address_space(3))) void*)l, 16, 0, 0);
}

DEV float gelu_tanh(float x){
  float u = 0.7978845608028654f * (x + 0.044715f * x * x * x);
  float e = __expf(2.0f * u);
  float th = 1.0f - 2.0f / (e + 1.0f);   // tanh(u), inf-safe
  return 0.5f * x * (1.0f + th);
}

// T1 XCD chunking + GW=16 column-grouped within-chunk mapping.
DEV void block_map(int bid, int nwg, int gx, int& tx, int& ty){
  const int swz = ((nwg & 7) == 0) ? ((bid & 7) * (nwg >> 3) + (bid >> 3)) : bid;
  const int gy = nwg / gx;
  const int cg = swz / (gy * 16);
  const int rr = swz - cg * gy * 16;
  const int gw = min(16, gx - cg * 16);
  tx = cg * 16 + rr % gw;
  ty = rr / gw;
}

// ---------------- weight cast + transpose: W[K,N] f32 -> Wt[N,K] bf16 ----------------
__global__ __launch_bounds__(256) void wtrans(const float* __restrict__ W,
                                              unsigned short* __restrict__ Wt,
                                              int K, int N){
  __shared__ float t[32][33];
  const int n0 = blockIdx.x * 32, k0 = blockIdx.y * 32;
  const int tx = threadIdx.x, ty = threadIdx.y;   // (32,8)
  #pragma unroll
  for (int i = 0; i < 4; i++)
    t[ty + i*8][tx] = W[(long)(k0 + ty + i*8) * N + n0 + tx];
  __syncthreads();
  #pragma unroll
  for (int i = 0; i < 4; i++)
    Wt[(long)(n0 + ty + i*8) * K + k0 + tx] = f2bf(t[tx][ty + i*8]);
}

// ---------------- LayerNorm over D=1024 rows: f32 in -> bf16 out ----------------
__global__ __launch_bounds__(256) void ln_rows(const float* __restrict__ in,
                                               const float* __restrict__ g,
                                               const float* __restrict__ beta,
                                               unsigned short* __restrict__ out){
  const long row = blockIdx.x;
  const int t = threadIdx.x;
  const float4 v = ((const float4*)(in + row * 1024))[t];
  float s  = v.x + v.y + v.z + v.w;
  float s2 = v.x*v.x + v.y*v.y + v.z*v.z + v.w*v.w;
  #pragma unroll
  for (int o = 32; o; o >>= 1){ s += __shfl_xor(s, o); s2 += __shfl_xor(s2, o); }
  __shared__ float rs[4], rq[4];
  const int wv = t >> 6;
  if ((t & 63) == 0){ rs[wv] = s; rq[wv] = s2; }
  __syncthreads();
  s  = rs[0] + rs[1] + rs[2] + rs[3];
  s2 = rq[0] + rq[1] + rq[2] + rq[3];
  const float mean = s * (1.f/1024.f);
  const float inv = rsqrtf(s2 * (1.f/1024.f) - mean*mean + 1e-6f);
  const float4 gv = ((const float4*)g)[t];
  const float4 bv = ((const float4*)beta)[t];
  ushort4 o4;
  o4.x = f2bf((v.x - mean)*inv*gv.x + bv.x);
  o4.y = f2bf((v.y - mean)*inv*gv.y + bv.y);
  o4.z = f2bf((v.z - mean)*inv*gv.z + bv.z);
  o4.w = f2bf((v.w - mean)*inv*gv.w + bv.w);
  *(ushort4*)(out + row * 1024 + t * 4) = o4;
}

// ---------------- V transpose per head: qkvVf [4608][1024] f32 -> Vt [BH][64][576] bf16 ----------------
__global__ __launch_bounds__(256) void v_trans(const float* __restrict__ qkvVf,
                                               unsigned short* __restrict__ Vt){
  const int bh = blockIdx.x, pt = blockIdx.y;   // pt: 0..8 (64 p's each)
  const int b = bh >> 4, h = bh & 15;
  __shared__ float tile[64][65];
  const int t = threadIdx.x;
  #pragma unroll
  for (int i = 0; i < 16; i++){
    int idx = i * 256 + t; int p = idx >> 6, d = idx & 63;
    tile[p][d] = qkvVf[((long)(b * 576) + pt * 64 + p) * 1024 + h * 64 + d];
  }
  __syncthreads();
  #pragma unroll
  for (int i = 0; i < 16; i++){
    int idx = i * 256 + t; int d = idx >> 6, p = idx & 63;
    Vt[((long)bh * 64 + d) * 576 + pt * 64 + p] = f2bf(tile[p][d]);
  }
}

// ---------------- attention: one block = one (bh, 16-q-row tile) ----------------
__global__ __launch_bounds__(256) void attn_k(const unsigned short* __restrict__ Qn,
                                              const unsigned short* __restrict__ Kn,
                                              const unsigned short* __restrict__ Vt,
                                              float* __restrict__ O){
  const int qb = blockIdx.x;
  const int bh = blockIdx.y;
  const int b = bh >> 4, h = bh & 15;
  const int tid = threadIdx.x, wv = tid >> 6, lane = tid & 63;
  const int fr = lane & 15, fq = lane >> 4;
  __shared__ float S[16][578];
  __shared__ __align__(16) unsigned short Pl[16][584];

  const unsigned short* qbase = Qn + ((long)bh * 576 + qb * 16 + fr) * 64;
  frag8 qf0 = *(const frag8*)(qbase + fq * 8);
  frag8 qf1 = *(const frag8*)(qbase + 32 + fq * 8);

  for (int i = 0; i < 9; i++){
    const int kt = wv + 4 * i;
    const unsigned short* kbase = Kn + ((long)bh * 576 + kt * 16 + fr) * 64;
    frag8 kf0 = *(const frag8*)(kbase + fq * 8);
    frag8 kf1 = *(const frag8*)(kbase + 32 + fq * 8);
    accf4 a = {0.f, 0.f, 0.f, 0.f};
    a = __builtin_amdgcn_mfma_f32_16x16x32_bf16(qf0, kf0, a, 0, 0, 0);
    a = __builtin_amdgcn_mfma_f32_16x16x32_bf16(qf1, kf1, a, 0, 0, 0);
    #pragma unroll
    for (int rr = 0; rr < 4; rr++) S[fq * 4 + rr][kt * 16 + fr] = a[rr];
  }
  __syncthreads();

  {
    const int row = tid >> 4, cid = tid & 15;
    float vals[36];
    float mx = -1e30f;
    #pragma unroll
    for (int i = 0; i < 36; i++){ vals[i] = S[row][cid + 16 * i]; mx = fmaxf(mx, vals[i]); }
    #pragma unroll
    for (int o = 8; o; o >>= 1) mx = fmaxf(mx, __shfl_xor(mx, o));
    float sum = 0.f;
    #pragma unroll
    for (int i = 0; i < 36; i++){ vals[i] = __expf(vals[i] - mx); sum += vals[i]; }
    #pragma unroll
    for (int o = 8; o; o >>= 1) sum += __shfl_xor(sum, o);
    const float rsum = 1.f / sum;
    #pragma unroll
    for (int i = 0; i < 36; i++) Pl[row][cid + 16 * i] = f2bf(vals[i] * rsum);
  }
  __syncthreads();

  accf4 oa = {0.f, 0.f, 0.f, 0.f};
  for (int kt = 0; kt < 18; kt++){
    frag8 pf = *(const frag8*)&Pl[fr][kt * 32 + fq * 8];
    const unsigned short* vb = Vt + ((long)bh * 64 + wv * 16 + fr) * 576 + kt * 32 + fq * 8;
    frag8 vf = *(const frag8*)vb;
    oa = __builtin_amdgcn_mfma_f32_16x16x32_bf16(pf, vf, oa, 0, 0, 0);
  }
  #pragma unroll
  for (int rr = 0; rr < 4; rr++){
    const long orow = (long)b * 576 + qb * 16 + fq * 4 + rr;
    O[orow * 1024 + h * 64 + wv * 16 + fr] = oa[rr];
  }
}

// ---------------- 256x256 8-wave BK=64 GEMM, minimum-2-phase, fused QK-LN (QKV) ----------------
__global__ __launch_bounds__(512) void gemm256(
    const unsigned short* __restrict__ Ag, const unsigned short* __restrict__ Btg,
    const float* __restrict__ qg, const float* __restrict__ qb2,
    const float* __restrict__ kg, const float* __restrict__ kb2,
    unsigned short* __restrict__ Qn, unsigned short* __restrict__ Kn,
    float* __restrict__ Vf, int K, int gx)
{
  __shared__ __align__(16) unsigned short As[2][256 * 64];
  __shared__ __align__(16) unsigned short Bs[2][256 * 64];
  const int tid = threadIdx.x;
  const int w = tid >> 6, l = tid & 63;
  const int fr = l & 15, fq = l >> 4;
  const int wr = w >> 2, wc = w & 3;          // 2 x 4 wave grid, wave tile 128x64
  const int rsw = fr & 7;
  const int nwg = gridDim.x, bid = blockIdx.x;
  const int swz = ((nwg & 7) == 0) ? ((bid & 7) * (nwg >> 3) + (bid >> 3)) : bid;
  const int tx = swz % gx, ty = swz / gx;
  const long rowbase = (long)ty * 256;
  const long colbase = (long)tx * 256;

  const int r8 = l >> 3;
  const int kq = (l & 7) ^ r8;
  const unsigned short* aS = Ag + (rowbase + w*32 + r8) * (long)K + kq * 8;
  const unsigned short* bS = Btg + (colbase + w*32 + r8) * (long)K + kq * 8;

  accf4 acc[8][4];
  const accf4 zero = {0.f, 0.f, 0.f, 0.f};
  #pragma unroll
  for (int m = 0; m < 8; m++)
    #pragma unroll
    for (int n = 0; n < 4; n++) acc[m][n] = zero;

  auto stage = [&](int d, int t){
    const long k0 = (long)t * 64;
    #pragma unroll
    for (int s = 0; s < 4; s++)
      gload16(aS + (long)s * 8 * K + k0, &As[d][w * 2048 + s * 512]);
    #pragma unroll
    for (int s = 0; s < 4; s++)
      gload16(bS + (long)s * 8 * K + k0, &Bs[d][w * 2048 + s * 512]);
  };
  auto compute = [&](int d){
    #pragma unroll
    for (int kk = 0; kk < 2; kk++){
      const int csw = ((kk * 4 + fq) ^ rsw) * 8;
      frag8 bf[4];
      #pragma unroll
      for (int nj = 0; nj < 4; nj++)
        bf[nj] = *(const frag8*)&Bs[d][(wc*64 + nj*16 + fr) * 64 + csw];
      #pragma unroll
      for (int mi = 0; mi < 8; mi++){
        frag8 af = *(const frag8*)&As[d][(wr*128 + mi*16 + fr) * 64 + csw];
        #pragma unroll
        for (int nj = 0; nj < 4; nj++)
          acc[mi][nj] = __builtin_amdgcn_mfma_f32_16x16x32_bf16(af, bf[nj], acc[mi][nj], 0, 0, 0);
      }
    }
  };

  const int NT = K >> 6;
  stage(0, 0);
  __syncthreads();
  int cur = 0;
  for (int t = 0; t < NT; ++t){
    if (t + 1 < NT) stage(cur ^ 1, t + 1);
    compute(cur);
    __syncthreads();
    cur ^= 1;
  }

  const int cg = (int)colbase + wc * 64;
  const int kind = cg >> 10;                   // 0=Q, 1=K, 2=V
  if (kind < 2){
    const float* g  = kind ? kg : qg;
    const float* bb = kind ? kb2 : qb2;
    const float sc = kind ? 1.0f : 0.125f;
    unsigned short* Out = kind ? Kn : Qn;
    const int h = (cg & 1023) >> 6;
    #pragma unroll
    for (int mi = 0; mi < 8; mi++){
      #pragma unroll
      for (int r = 0; r < 4; r++){
        float s1 = 0.f, s2 = 0.f;
        #pragma unroll
        for (int nj = 0; nj < 4; nj++){ const float v = acc[mi][nj][r]; s1 += v; s2 += v*v; }
        #pragma unroll
        for (int o = 8; o; o >>= 1){ s1 += __shfl_xor(s1, o); s2 += __shfl_xor(s2, o); }
        const float mean = s1 * (1.f/64.f);
        const float inv = rsqrtf(s2 * (1.f/64.f) - mean*mean + 1e-6f);
        const long row = rowbase + wr*128 + mi*16 + fq*4 + r;
        const int bq = (int)(row / 576), p = (int)(row - (long)bq*576);
        unsigned short* dst = Out + (((long)(bq*16 + h))*576 + p)*64;
        #pragma unroll
        for (int nj = 0; nj < 4; nj++){
          const int d = nj*16 + fr;
          dst[d] = f2bf(((acc[mi][nj][r] - mean)*inv*g[d] + bb[d]) * sc);
        }
      }
    }
  } else {
    #pragma unroll
    for (int mi = 0; mi < 8; mi++){
      const long rb = rowbase + wr*128 + mi*16 + fq*4;
      #pragma unroll
      for (int nj = 0; nj < 4; nj++){
        const int vc = (cg - 2048) + nj*16 + fr;
        #pragma unroll
        for (int r = 0; r < 4; r++)
          Vf[(rb + r)*1024 + vc] = acc[mi][nj][r];
      }
    }
  }
}

// ---------------- 128xBN 4-wave BK=64 GEMM, minimum-2-phase + T2 ----------------
// BN=128 (MLP1, EPI2: gelu->bf16) LDS 64KB -> 2 blocks/CU.
// BN=64 (proj/MLP2, EPI1: resid+(acc+bias)*ls) LDS 48KB -> 3 blocks/CU.
// stage(t+1) before compute(t); one __syncthreads per K-step. T2: chunk c of row r
// stored at c^(r&7) (inverse on global source, LDS dest linear; read 2-way = free).
template<int BN, int EPI>
__global__ __launch_bounds__(256) void gemm_bk64(
    const unsigned short* __restrict__ A, const unsigned short* __restrict__ Bt,
    float* __restrict__ Cf, unsigned short* __restrict__ Cb,
    const float* __restrict__ bias, const float* __restrict__ ls,
    const float* __restrict__ resid, int M, int N, int K, int gx)
{
  constexpr int NF = BN / 32;            // B frags per wave-col
  constexpr int BSLOT = BN / 32;         // B stage slots per wave
  __shared__ __align__(16) unsigned short As[2][128 * 64];
  __shared__ __align__(16) unsigned short Bs[2][BN * 64];
  const int tid = threadIdx.x;
  const int wave = tid >> 6, l = tid & 63;
  const int fr = l & 15, fq = l >> 4;
  const int wr = wave >> 1, wc = wave & 1;
  const int rsw = fr & 7;
  int tx, ty;
  block_map(blockIdx.x, gridDim.x, gx, tx, ty);
  const long rowbase = (long)ty * 128;
  const long colbase = (long)tx * BN;

  const int r8 = l >> 3;
  const int kq = (l & 7) ^ r8;
  const unsigned short* aS = A + (rowbase + wave*32 + r8) * (long)K + kq * 8;
  const unsigned short* bS = Bt + (colbase + wave*(BN/4) + r8) * (long)K + kq * 8;

  accf4 acc[4][NF];
  const accf4 zero = {0.f, 0.f, 0.f, 0.f};
  #pragma unroll
  for (int m = 0; m < 4; m++)
    #pragma unroll
    for (int n = 0; n < NF; n++) acc[m][n] = zero;

  auto stage = [&](int d, int t){
    const long k0 = (long)t * 64;
    #pragma unroll
    for (int s = 0; s < 4; s++)
      gload16(aS + (long)s * 8 * K + k0, &As[d][(wave*4 + s) * 512]);
    #pragma unroll
    for (int s = 0; s < BSLOT; s++)
      gload16(bS + (long)s * 8 * K + k0, &Bs[d][(wave*BSLOT + s) * 512]);
  };
  auto compute = [&](int d){
    #pragma unroll
    for (int kk = 0; kk < 2; kk++){
      const int csw = ((kk * 4 + fq) ^ rsw) * 8;
      frag8 bf[NF];
      #pragma unroll
      for (int n = 0; n < NF; n++)
        bf[n] = *(const frag8*)&Bs[d][(wc*(BN/2) + n*16 + fr) * 64 + csw];
      #pragma unroll
      for (int m = 0; m < 4; m++){
        frag8 af = *(const frag8*)&As[d][(wr*64 + m*16 + fr) * 64 + csw];
        #pragma unroll
        for (int n = 0; n < NF; n++)
          acc[m][n] = __builtin_amdgcn_mfma_f32_16x16x32_bf16(af, bf[n], acc[m][n], 0, 0, 0);
      }
    }
  };

  const int NT = K >> 6;
  stage(0, 0);
  __syncthreads();
  int cur = 0;
  for (int t = 0; t < NT; ++t){
    if (t + 1 < NT) stage(cur ^ 1, t + 1);
    compute(cur);
    __syncthreads();
    cur ^= 1;
  }

  #pragma unroll
  for (int m = 0; m < 4; m++){
    const long rb = rowbase + wr * 64 + m * 16 + fq * 4;
    #pragma unroll
    for (int n = 0; n < NF; n++){
      const long cb = colbase + wc * (BN/2) + n * 16 + fr;
      #pragma unroll
      for (int r = 0; r < 4; r++){
        const long idx = (rb + r) * N + cb;
        const float v = acc[m][n][r];
        if constexpr (EPI == 1){
          Cf[idx] = resid[idx] + (v + bias[cb]) * ls[cb];
        } else {
          Cb[idx] = f2bf(gelu_tanh(v + bias[cb]));
        }
      }
    }
  }
}

extern "C" void kernel_launch(void* const* d_in, const int* in_sizes, int n_in,
                              void* d_out, int out_size, void* d_ws, size_t ws_size,
                              hipStream_t stream){
  (void)in_sizes; (void)n_in; (void)out_size; (void)ws_size;
  const float* x      = (const float*)d_in[0];
  const float* w_qkv  = (const float*)d_in[1];
  const float* q_g    = (const float*)d_in[2];
  const float* q_b    = (const float*)d_in[3];
  const float* k_g    = (const float*)d_in[4];
  const float* k_b    = (const float*)d_in[5];
  const float* o_g    = (const float*)d_in[6];
  const float* o_b    = (const float*)d_in[7];
  const float* w_proj = (const float*)d_in[8];
  const float* b_proj = (const float*)d_in[9];
  const float* ln1_g  = (const float*)d_in[10];
  const float* ln1_b  = (const float*)d_in[11];
  const float* ln2_g  = (const float*)d_in[12];
  const float* ln2_b  = (const float*)d_in[13];
  const float* w1     = (const float*)d_in[14];
  const float* b1     = (const float*)d_in[15];
  const float* w2     = (const float*)d_in[16];
  const float* b2     = (const float*)d_in[17];
  const float* ls1    = (const float*)d_in[18];
  const float* ls2    = (const float*)d_in[19];
  float* out = (float*)d_out;

  char* ws = (char*)d_ws;
  size_t off = 0;
  auto alloc = [&](size_t bytes)->void*{
    void* p = ws + off; off += (bytes + 255) & ~(size_t)255; return p;
  };
  unsigned short* wqkvT  = (unsigned short*)alloc(3072l*1024*2);
  unsigned short* wprojT = (unsigned short*)alloc(1024l*1024*2);
  unsigned short* w1T    = (unsigned short*)alloc(4096l*1024*2);
  unsigned short* w2T    = (unsigned short*)alloc(1024l*4096*2);
  unsigned short* xnA    = (unsigned short*)alloc(4608l*1024*2);   // xn1 / on / xn2
  float*          qkvVf  = (float*)alloc(4608l*1024*4);            // V third, f32
  unsigned short* Qn     = (unsigned short*)alloc(73728l*64*2);
  unsigned short* Kn     = (unsigned short*)alloc(73728l*64*2);
  unsigned short* Vt     = (unsigned short*)alloc(73728l*64*2);
  unsigned short* hbf    = (unsigned short*)alloc(4608l*4096*2);
  float*          attnO  = qkvVf;   // overlay: qkvVf dead after v_trans

  // weights -> bf16 B^T
  wtrans<<<dim3(3072/32, 1024/32), dim3(32,8), 0, stream>>>(w_qkv,  wqkvT,  1024, 3072);
  wtrans<<<dim3(1024/32, 1024/32), dim3(32,8), 0, stream>>>(w_proj, wprojT, 1024, 1024);
  wtrans<<<dim3(4096/32, 1024/32), dim3(32,8), 0, stream>>>(w1,     w1T,    1024, 4096);
  wtrans<<<dim3(1024/32, 4096/32), dim3(32,8), 0, stream>>>(w2,     w2T,    4096, 1024);

  // attention branch
  ln_rows<<<4608, 256, 0, stream>>>(x, ln1_g, ln1_b, xnA);
  gemm256<<<18*12, 512, 0, stream>>>(xnA, wqkvT,
                                     q_g, q_b, k_g, k_b, Qn, Kn, qkvVf,
                                     1024, 12);
  v_trans<<<dim3(128,9), 256, 0, stream>>>(qkvVf, Vt);
  attn_k<<<dim3(36,128), 256, 0, stream>>>(Qn, Kn, Vt, attnO);
  ln_rows<<<4608, 256, 0, stream>>>(attnO, o_g, o_b, xnA);
  gemm_bk64<64,1><<<16*36, 256, 0, stream>>>(xnA, wprojT, out, nullptr,
                                             b_proj, ls1, x, 4608, 1024, 1024, 16);
  // MLP branch
  ln_rows<<<4608, 256, 0, stream>>>(out, ln2_g, ln2_b, xnA);
  gemm_bk64<128,2><<<32*36, 256, 0, stream>>>(xnA, w1T, nullptr, hbf,
                                              b1, nullptr, nullptr, 4608, 4096, 1024, 32);
  gemm_bk64<64,1><<<16*36, 256, 0, stream>>>(hbf, w2T, out, nullptr,
                                             b2, ls2, out, 4608, 1024, 4096, 16);
}